// Round 1
// 1196.725 us; speedup vs baseline: 3.6626x; 3.6626x over previous
//
#include <hip/hip_runtime.h>
#include <hip/hip_bf16.h>
#include <cstdio>
#include <math.h>

// GraphAttention forward, MI355X/gfx950.  Inputs/outputs FLOAT32.
// out0: bf16 MFMA path (PASSES at 2e-2).
// out1: EXACT numpy-fp32 emulation (established R4-R6: fp64 is not enough; the
// binary threshold decisions require bit-identical fp32):
//   - einsum sums (feats over f, logits over k, temp over j): SSE 4-lane 1-acc
//     dot, lane = idx%4, hsum ((a0+a1)+(a2+a3))
//   - np.sum reductions: numpy pairwise_sum, AVX512 base case
//   - exp/sigmoid: correctly-rounded fp32 via fp64 exp
//   - all fp32 ops via __f*_rn (no FMA contraction)
//
// R7 (this round): feats32_emu was 45% of total at VALUBusy=17% — latency-bound
// on 1 load per VALU op (kern stride-256B from L2, X broadcast). Re-mapped to
// lane=row / 8-k-per-thread: kern addresses wave-uniform (scalar loads, shared
// by 64 lanes), X per-lane float4 with full-cache-line consumption, each X
// value reused 8x in registers. Per-output FADD/FMUL chains bit-identical.
// Instrumentation kernels (margin_stats/probe_out) removed.

typedef __attribute__((ext_vector_type(8))) short   s16x8;
typedef __attribute__((ext_vector_type(8))) __bf16  bf16x8;
typedef __attribute__((ext_vector_type(4))) float   fx4;

#define FADD __fadd_rn
#define FMUL __fmul_rn
#define FSUB __fsub_rn
#define FDIV __fdiv_rn
#define MASKC (-9999998976.0f)   // fl32(-1e10)

__device__ __forceinline__ fx4 mfma_bf16_16x16x32(s16x8 a, s16x8 b, fx4 c) {
    return __builtin_amdgcn_mfma_f32_16x16x32_bf16(
        __builtin_bit_cast(bf16x8, a), __builtin_bit_cast(bf16x8, b), c, 0, 0, 0);
}
__device__ __forceinline__ unsigned short f2bf(float f) {
    unsigned int x = __builtin_bit_cast(unsigned int, f);
    unsigned int lsb = (x >> 16) & 1u;
    x += 0x7fffu + lsb;
    return (unsigned short)(x >> 16);
}
__device__ __forceinline__ unsigned int pack2(float a, float b) {
    return (unsigned int)f2bf(a) | ((unsigned int)f2bf(b) << 16);
}
__device__ __forceinline__ float expf_cr(float x) {   // correctly-rounded expf
    return (float)exp((double)x);
}

// numpy pairwise_sum base (n=128), AVX512 flavor:
// 8 chunk-accumulators (16 lanes), combine ((r0+r1)+(r2+r3))+((r4+r5)+(r6+r7)),
// then _mm512_reduce_add_ps halving tree.
__device__ float pw128(const float* a) {
    float c[16];
#pragma unroll
    for (int l = 0; l < 16; ++l) {
        float t0 = FADD(FADD(a[l], a[16 + l]), FADD(a[32 + l], a[48 + l]));
        float t1 = FADD(FADD(a[64 + l], a[80 + l]), FADD(a[96 + l], a[112 + l]));
        c[l] = FADD(t0, t1);
    }
    float d[8], e[4], f[2];
#pragma unroll
    for (int l = 0; l < 8; ++l) d[l] = FADD(c[l], c[l + 8]);
#pragma unroll
    for (int l = 0; l < 4; ++l) e[l] = FADD(d[l], d[l + 4]);
#pragma unroll
    for (int l = 0; l < 2; ++l) f[l] = FADD(e[l], e[l + 2]);
    return FADD(f[0], f[1]);
}

// ---------------------------------------------------------------- out0 support
__global__ __launch_bounds__(256) void repack_w(const float* __restrict__ kern,
                                                unsigned short* __restrict__ wkt) {
    int t = blockIdx.x * 256 + threadIdx.x;
    int n = t >> 9, f = t & 511;
    int h = n >> 6, k = n & 63;
    wkt[t] = f2bf(kern[(h * 512 + f) * 64 + k]);
}

#define BK 32
__global__ __launch_bounds__(256) void gemm_feats(const float* __restrict__ X,
                                                  const unsigned short* __restrict__ Wkt,
                                                  unsigned short* __restrict__ feats_bf) {
    __shared__ alignas(16) unsigned short As[128 * BK];
    __shared__ alignas(16) unsigned short Bs[128 * BK];
    const int tid = threadIdx.x;
    const int mb = blockIdx.x >> 2, nb = blockIdx.x & 3;
    const int m0 = mb * 128, n0 = nb * 128;
    const int w = tid >> 6, lane = tid & 63;
    const int mw = (w & 1) * 64, nw = (w >> 1) * 64;
    const int lr = lane & 15, lq = lane >> 4;
    const int srow = tid >> 2, scol = (tid & 3) * 8;

    fx4 acc[4][4] = {};
    for (int k0 = 0; k0 < 512; k0 += BK) {
        __syncthreads();
        {
            const float* xr0 = &X[(m0 + srow) * 512 + k0 + scol];
            const float* xr1 = &X[(m0 + srow + 64) * 512 + k0 + scol];
            float4 a0 = *(const float4*)xr0, a1 = *(const float4*)(xr0 + 4);
            float4 b0 = *(const float4*)xr1, b1 = *(const float4*)(xr1 + 4);
            uint4 p0 = { pack2(a0.x, a0.y), pack2(a0.z, a0.w), pack2(a1.x, a1.y), pack2(a1.z, a1.w) };
            uint4 p1 = { pack2(b0.x, b0.y), pack2(b0.z, b0.w), pack2(b1.x, b1.y), pack2(b1.z, b1.w) };
            *(uint4*)&As[srow * BK + scol]        = p0;
            *(uint4*)&As[(srow + 64) * BK + scol] = p1;
            *(uint4*)&Bs[srow * BK + scol]        = *(const uint4*)&Wkt[(n0 + srow) * 512 + k0 + scol];
            *(uint4*)&Bs[(srow + 64) * BK + scol] = *(const uint4*)&Wkt[(n0 + srow + 64) * 512 + k0 + scol];
        }
        __syncthreads();
        s16x8 a[4], bb[4];
#pragma unroll
        for (int i = 0; i < 4; ++i) a[i]  = *(const s16x8*)&As[(mw + i * 16 + lr) * BK + lq * 8];
#pragma unroll
        for (int i = 0; i < 4; ++i) bb[i] = *(const s16x8*)&Bs[(nw + i * 16 + lr) * BK + lq * 8];
#pragma unroll
        for (int i = 0; i < 4; ++i)
#pragma unroll
            for (int j = 0; j < 4; ++j)
                acc[i][j] = mfma_bf16_16x16x32(a[i], bb[j], acc[i][j]);
    }
#pragma unroll
    for (int i = 0; i < 4; ++i)
#pragma unroll
        for (int j = 0; j < 4; ++j) {
            int col  = n0 + nw + j * 16 + lr;
            int rowb = m0 + mw + i * 16 + lq * 4;
#pragma unroll
            for (int r = 0; r < 4; ++r)
                feats_bf[(rowb + r) * 512 + col] = f2bf(acc[i][j][r]);
        }
}

// ---------------------------------------------------------------- feats32 (np emu, v2)
// feats32[h][row][k] = SSE-dot over f: lane = f%4, acc_l += x*w (order f, f+4), hsum.
// Mapping: lane = row (64 rows/wave), 8 k per thread (k-group from blockIdx →
// kern addresses wave-uniform → scalar loads broadcast via SGPRs). X loaded
// per-lane as float4, f unrolled by 32 so each 128B line is consumed in one
// visit; every X value reused for 8 accumulator chains in registers.
// Per-output arithmetic sequence identical to v1.
__global__ __launch_bounds__(256) void feats32_emu2(const float* __restrict__ X,
                                                    const float* __restrict__ kern,
                                                    float* __restrict__ feats32) {
    // grid: 8 h * 8 kg * 128 rb = 8192 blocks of 256 threads
    const int bid = blockIdx.x;
    const int rb = bid & 127, kg = (bid >> 7) & 7, h = bid >> 10;
    const int row = rb * 256 + threadIdx.x;
    const int k0 = kg * 8;
    const float* __restrict__ xr = &X[row * 512];               // per-lane
    const float* __restrict__ kp = &kern[h * 512 * 64 + k0];    // wave-uniform

    float acc[8][4];
#pragma unroll
    for (int q = 0; q < 8; ++q)
#pragma unroll
        for (int l = 0; l < 4; ++l) acc[q][l] = 0.f;

    for (int f = 0; f < 512; f += 32) {
        float xv[32];
#pragma unroll
        for (int u = 0; u < 8; ++u) {
            float4 t = *(const float4*)&xr[f + u * 4];
            xv[u * 4 + 0] = t.x; xv[u * 4 + 1] = t.y;
            xv[u * 4 + 2] = t.z; xv[u * 4 + 3] = t.w;
        }
#pragma unroll
        for (int jb = 0; jb < 4; ++jb) {
            const int fb = f + jb * 8;
            float w[8][8];
#pragma unroll
            for (int j = 0; j < 8; ++j) {
                float4 lo = *(const float4*)&kp[(fb + j) * 64];
                float4 hi = *(const float4*)&kp[(fb + j) * 64 + 4];
                w[j][0] = lo.x; w[j][1] = lo.y; w[j][2] = lo.z; w[j][3] = lo.w;
                w[j][4] = hi.x; w[j][5] = hi.y; w[j][6] = hi.z; w[j][7] = hi.w;
            }
#pragma unroll
            for (int q = 0; q < 8; ++q) {
                const int xb = jb * 8;
                acc[q][0] = FADD(acc[q][0], FMUL(xv[xb + 0], w[0][q]));
                acc[q][1] = FADD(acc[q][1], FMUL(xv[xb + 1], w[1][q]));
                acc[q][2] = FADD(acc[q][2], FMUL(xv[xb + 2], w[2][q]));
                acc[q][3] = FADD(acc[q][3], FMUL(xv[xb + 3], w[3][q]));
                acc[q][0] = FADD(acc[q][0], FMUL(xv[xb + 4], w[4][q]));
                acc[q][1] = FADD(acc[q][1], FMUL(xv[xb + 5], w[5][q]));
                acc[q][2] = FADD(acc[q][2], FMUL(xv[xb + 6], w[6][q]));
                acc[q][3] = FADD(acc[q][3], FMUL(xv[xb + 7], w[7][q]));
            }
        }
    }

    float* __restrict__ op = &feats32[(h * 32768 + row) * 64 + k0];
    float4 o0, o1;
    o0.x = FADD(FADD(acc[0][0], acc[0][1]), FADD(acc[0][2], acc[0][3]));
    o0.y = FADD(FADD(acc[1][0], acc[1][1]), FADD(acc[1][2], acc[1][3]));
    o0.z = FADD(FADD(acc[2][0], acc[2][1]), FADD(acc[2][2], acc[2][3]));
    o0.w = FADD(FADD(acc[3][0], acc[3][1]), FADD(acc[3][2], acc[3][3]));
    o1.x = FADD(FADD(acc[4][0], acc[4][1]), FADD(acc[4][2], acc[4][3]));
    o1.y = FADD(FADD(acc[5][0], acc[5][1]), FADD(acc[5][2], acc[5][3]));
    o1.z = FADD(FADD(acc[6][0], acc[6][1]), FADD(acc[6][2], acc[6][3]));
    o1.w = FADD(FADD(acc[7][0], acc[7][1]), FADD(acc[7][2], acc[7][3]));
    *(float4*)&op[0] = o0;
    *(float4*)&op[4] = o1;
}

// ---------------------------------------------------------------- logits (np emu)
__device__ float sse_dot64(const float* __restrict__ x, const float* __restrict__ y) {
    float a0 = 0.f, a1 = 0.f, a2 = 0.f, a3 = 0.f;
    for (int i = 0; i < 64; i += 8) {
        a0 = FADD(a0, FMUL(x[i + 0], y[i + 0]));
        a1 = FADD(a1, FMUL(x[i + 1], y[i + 1]));
        a2 = FADD(a2, FMUL(x[i + 2], y[i + 2]));
        a3 = FADD(a3, FMUL(x[i + 3], y[i + 3]));
        a0 = FADD(a0, FMUL(x[i + 4], y[i + 4]));
        a1 = FADD(a1, FMUL(x[i + 5], y[i + 5]));
        a2 = FADD(a2, FMUL(x[i + 6], y[i + 6]));
        a3 = FADD(a3, FMUL(x[i + 7], y[i + 7]));
    }
    return FADD(FADD(a0, a1), FADD(a2, a3));
}

__global__ __launch_bounds__(256) void logits_emu(const float* __restrict__ feats32,
                                                  const float* __restrict__ attn_s,
                                                  const float* __restrict__ attn_n,
                                                  float* __restrict__ a_s32,
                                                  float* __restrict__ a_n32) {
    int t = blockIdx.x * 256 + threadIdx.x;      // 262,144
    int row = t & 32767, h = t >> 15;
    const float* fr = &feats32[(h * 32768 + row) * 64];
    a_s32[h * 32768 + row] = sse_dot64(fr, &attn_s[h * 64]);
    a_n32[h * 32768 + row] = sse_dot64(fr, &attn_n[h * 64]);
}

// ---------------------------------------------------------------- attention (np-fp32 emu)
#define VT_STRIDE 264
#define AS_STRIDE 264
__global__ __launch_bounds__(256) void attn_emu(const float* __restrict__ A,
                                                const unsigned short* __restrict__ feats_bf,
                                                const float* __restrict__ a_s32,
                                                const float* __restrict__ a_n32,
                                                const float* __restrict__ biases,
                                                float* __restrict__ out0,
                                                float* __restrict__ view32) {
    __shared__ alignas(16) unsigned short Vt[64 * VT_STRIDE];   // 33792 B
    __shared__ alignas(4)  unsigned char  Asm[64 * AS_STRIDE];  // 16896 B
    __shared__ float an_l[8][256];                              //  8192 B
    __shared__ float as_l[8][64];                               //  2048 B
    __shared__ float Msh[8][64];                                //  2048 B
    __shared__ float Ssh[8][64];                                //  2048 B  = 65024 B

    const int tid = threadIdx.x;
    const int b = blockIdx.x >> 2;
    const int row0 = (blockIdx.x & 3) * 64;
    const int w = tid >> 6, lane = tid & 63;
    const int m = lane & 15, jq = lane >> 4;

    // stage adjacency as bytes
#pragma unroll
    for (int l = 0; l < 16; ++l) {
        int lin = tid + l * 256;
        int i = lin >> 6, jf = lin & 63;
        float4 av = *(const float4*)&A[(((b << 8) + row0 + i) << 8) + jf * 4];
        unsigned int bits = (av.x != 0.f ? 1u : 0u) | (av.y != 0.f ? 0x100u : 0u) |
                            (av.z != 0.f ? 0x10000u : 0u) | (av.w != 0.f ? 0x1000000u : 0u);
        *(unsigned int*)&Asm[i * AS_STRIDE + jf * 4] = bits;
    }
    // stage logits (all heads)
    for (int idx = tid; idx < 2048; idx += 256) {
        int h = idx >> 8, j = idx & 255;
        an_l[h][j] = a_n32[h * 32768 + (b << 8) + j];
    }
    for (int idx = tid; idx < 512; idx += 256) {
        int h = idx >> 6, i = idx & 63;
        as_l[h][i] = a_s32[h * 32768 + (b << 8) + row0 + i];
    }
    __syncthreads();

    // Phase A: per (i, h) task — np-fp32 M and pairwise-S
#pragma unroll
    for (int rep = 0; rep < 2; ++rep) {
        int task = tid + rep * 256;              // 0..511
        int i = task & 63, h = task >> 6;
        float asv = as_l[h][i];
        const unsigned char* arow = &Asm[i * AS_STRIDE];
        float M = -3.4e38f;
        for (int j = 0; j < 256; ++j) {
            float lg = FADD(asv, an_l[h][j]);
            float lr = lg > 0.f ? lg : FMUL(0.2f, lg);
            float v  = arow[j] ? lr : FADD(lr, MASKC);
            M = fmaxf(M, v);
        }
        float S = 0.f;
#pragma unroll
        for (int blk = 0; blk < 2; ++blk) {
            int j0 = blk * 128;
            float c[16];
#pragma unroll
            for (int l = 0; l < 16; ++l) {
                float ev[8];
#pragma unroll
                for (int q = 0; q < 8; ++q) {
                    int j = j0 + q * 16 + l;
                    float lg = FADD(asv, an_l[h][j]);
                    float lr = lg > 0.f ? lg : FMUL(0.2f, lg);
                    float v  = arow[j] ? lr : FADD(lr, MASKC);
                    ev[q] = expf_cr(FSUB(v, M));
                }
                float t0 = FADD(FADD(ev[0], ev[1]), FADD(ev[2], ev[3]));
                float t1 = FADD(FADD(ev[4], ev[5]), FADD(ev[6], ev[7]));
                c[l] = FADD(t0, t1);
            }
            float d[8], e4[4], f2[2];
#pragma unroll
            for (int l = 0; l < 8; ++l) d[l] = FADD(c[l], c[l + 8]);
#pragma unroll
            for (int l = 0; l < 4; ++l) e4[l] = FADD(d[l], d[l + 4]);
#pragma unroll
            for (int l = 0; l < 2; ++l) f2[l] = FADD(e4[l], e4[l + 2]);
            float blkS = FADD(f2[0], f2[1]);
            S = (blk == 0) ? blkS : FADD(S, blkS);
        }
        Msh[h][i] = M;
        Ssh[h][i] = S;
    }
    __syncthreads();

    // Phase B: per head — p (np-fp32), view accumulate, PV MFMA for out0
    float view_acc[8][8] = {};
    const int myrow = row0 + w * 16 + m;
    const int i_ln = w * 16 + m;
    const unsigned char* arow = &Asm[i_ln * AS_STRIDE];

    for (int h = 0; h < 8; ++h) {
        __syncthreads();
        {
            int kk = lane, jb = w;
            for (int it = 0; it < 64; ++it) {
                int j = jb * 64 + it;
                Vt[kk * VT_STRIDE + j] = feats_bf[(((b << 8) + j) << 9) + (h << 6) + kk];
            }
        }
        __syncthreads();

        float asv = as_l[h][i_ln];
        float Mi = Msh[h][i_ln];
        float Si = Ssh[h][i_ln];

        s16x8 pfrag[8];
#pragma unroll
        for (int kb = 0; kb < 8; ++kb) {
            int jbase = kb * 32 + jq * 8;
            s16x8 pf;
#pragma unroll
            for (int t = 0; t < 8; ++t) {
                int j = jbase + t;
                float lg = FADD(asv, an_l[h][j]);
                float lr = lg > 0.f ? lg : FMUL(0.2f, lg);
                float v  = arow[j] ? lr : FADD(lr, MASKC);
                float e  = expf_cr(FSUB(v, Mi));
                float p  = FDIV(e, Si);
                view_acc[kb][t] = FADD(view_acc[kb][t], FMUL(p, 0.125f));
                pf[t] = (short)f2bf(p);
            }
            pfrag[kb] = pf;
        }

        fx4 acc[4] = {};
#pragma unroll
        for (int kb = 0; kb < 8; ++kb) {
            int jo = kb * 32 + jq * 8;
#pragma unroll
            for (int nf = 0; nf < 4; ++nf) {
                s16x8 vf = *(const s16x8*)&Vt[(nf * 16 + m) * VT_STRIDE + jo];
                acc[nf] = mfma_bf16_16x16x32(pfrag[kb], vf, acc[nf]);
            }
        }
#pragma unroll
        for (int nf = 0; nf < 4; ++nf) {
            float bias = biases[h * 64 + nf * 16 + m];
#pragma unroll
            for (int r = 0; r < 4; ++r) {
                float val = acc[nf][r] + bias;
                val = val > 0.f ? val : 0.f;
                int gi = (b << 8) + row0 + w * 16 + jq * 4 + r;
                out0[gi * 512 + h * 64 + nf * 16 + m] = val;
            }
        }
    }

#pragma unroll
    for (int kb = 0; kb < 8; ++kb) {
        int base = (((b << 8) + myrow) << 8) + kb * 32 + jq * 8;
        float4 v0, v1;
        v0.x = view_acc[kb][0]; v0.y = view_acc[kb][1]; v0.z = view_acc[kb][2]; v0.w = view_acc[kb][3];
        v1.x = view_acc[kb][4]; v1.y = view_acc[kb][5]; v1.z = view_acc[kb][6]; v1.w = view_acc[kb][7];
        *(float4*)&view32[base]     = v0;
        *(float4*)&view32[base + 4] = v1;
    }
}

// ---------------------------------------------------------------- pool / temp / thresh
__global__ __launch_bounds__(256) void pool_emu(const float* __restrict__ view32,
                                                float* __restrict__ pooled) {
    int t = blockIdx.x * 256 + threadIdx.x;      // 2,097,152
    int j = t & 127, i = (t >> 7) & 127, b = t >> 14;
    const float* p = &view32[(b << 16) + (2 * i) * 256 + 2 * j];
    pooled[t] = fmaxf(fmaxf(p[0], p[1]), fmaxf(p[256], p[257]));
}

// temp[b,i,k] = SSE dot over j=0..127: pooled row (contig) x alpha[:,k] (stride 128)
__global__ __launch_bounds__(256) void temp_emu(const float* __restrict__ pooled,
                                                const float* __restrict__ alpha,
                                                float* __restrict__ temp) {
    int t = blockIdx.x * 256 + threadIdx.x;      // 2,097,152
    int k = t & 127, i = (t >> 7) & 127, b = t >> 14;
    const float* pr = &pooled[(b << 14) + i * 128];
    const float* ap = &alpha[k];                  // stride 128 over j
    float a0 = 0.f, a1 = 0.f, a2 = 0.f, a3 = 0.f;
    for (int j = 0; j < 128; j += 8) {
        a0 = FADD(a0, FMUL(pr[j + 0], ap[(j + 0) * 128]));
        a1 = FADD(a1, FMUL(pr[j + 1], ap[(j + 1) * 128]));
        a2 = FADD(a2, FMUL(pr[j + 2], ap[(j + 2) * 128]));
        a3 = FADD(a3, FMUL(pr[j + 3], ap[(j + 3) * 128]));
        a0 = FADD(a0, FMUL(pr[j + 4], ap[(j + 4) * 128]));
        a1 = FADD(a1, FMUL(pr[j + 5], ap[(j + 5) * 128]));
        a2 = FADD(a2, FMUL(pr[j + 6], ap[(j + 6) * 128]));
        a3 = FADD(a3, FMUL(pr[j + 7], ap[(j + 7) * 128]));
    }
    temp[t] = FADD(FADD(a0, a1), FADD(a2, a3));
}

// s[b] = numpy pairwise over 16384 (128 leaves of pw128, balanced binary tree)
__global__ __launch_bounds__(128) void thresh_emu(const float* __restrict__ temp,
                                                  float* __restrict__ thresh32) {
    __shared__ float red[128];
    int l = threadIdx.x, b = blockIdx.x;
    red[l] = pw128(&temp[(b << 14) + l * 128]);
    __syncthreads();
    for (int s = 64; s >= 1; s >>= 1) {
        float v = 0.f;
        if (l < s) v = FADD(red[2 * l], red[2 * l + 1]);
        __syncthreads();
        if (l < s) red[l] = v;
        __syncthreads();
    }
    if (l == 0) {
        float sfin = red[0];
        float e = expf_cr(-sfin);                 // np.exp(-s) fp32 (correctly rounded)
        thresh32[b] = FDIV(1.0f, FADD(1.0f, e)); // 1/(1+e)
    }
}

// ---------------------------------------------------------------- binarize (fp32)
__global__ __launch_bounds__(256) void binarize_emu(const float* __restrict__ view32,
                                                    const float* __restrict__ thresh32,
                                                    float* __restrict__ out1) {
    int g = blockIdx.x * 256 + threadIdx.x;
    int e = g * 4;
    int b = e >> 16, i = (e >> 8) & 255, j = e & 255;
    float th = thresh32[b];
    float4 v = *(const float4*)&view32[e];
    float4 o;
    o.x = (FADD(v.x, (i == j + 0) ? 1.f : 0.f) < th) ? 1.f : 0.f;
    o.y = (FADD(v.y, (i == j + 1) ? 1.f : 0.f) < th) ? 1.f : 0.f;
    o.z = (FADD(v.z, (i == j + 2) ? 1.f : 0.f) < th) ? 1.f : 0.f;
    o.w = (FADD(v.w, (i == j + 3) ? 1.f : 0.f) < th) ? 1.f : 0.f;
    *(float4*)&out1[e] = o;
}

// ---------------------------------------------------------------- launch
static inline void ck_launch(const char* name) {
    hipError_t e = hipGetLastError();
    if (e != hipSuccess)
        fprintf(stderr, "[gat] %s launch error %d: %s\n", name, (int)e, hipGetErrorString(e));
}

extern "C" void kernel_launch(void* const* d_in, const int* in_sizes, int n_in,
                              void* d_out, int out_size, void* d_ws, size_t ws_size,
                              hipStream_t stream) {
    const float* X      = (const float*)d_in[0];
    const float* A      = (const float*)d_in[1];
    const float* kern   = (const float*)d_in[2];
    const float* biases = (const float*)d_in[3];
    const float* attn_s = (const float*)d_in[4];
    const float* attn_n = (const float*)d_in[5];
    const float* alpha  = (const float*)d_in[6];

    char* ws = (char*)d_ws;
    unsigned short* feats_bf = (unsigned short*)(ws);             //  33,554,432 B
    float*          feats32  = (float*)(ws + 33554432);           //  67,108,864 B
    float*          view32   = (float*)(ws + 100663296);          //  33,554,432 B
    float*          a_s32    = (float*)(ws + 134217728);          //   1,048,576 B
    float*          a_n32    = (float*)(ws + 135266304);          //   1,048,576 B
    float*          pooled   = (float*)(ws + 136314880);          //   8,388,608 B
    float*          temp     = (float*)(ws + 144703488);          //   8,388,608 B
    float*          thresh32 = (float*)(ws + 153092096);          //         512 B
    unsigned short* wkt      = (unsigned short*)(ws + 153092608); //     524,288 B

    float* out0 = (float*)d_out;
    float* out1 = out0 + 16777216;

    repack_w    <<<1024, 256, 0, stream>>>(kern, wkt);              ck_launch("repack_w");
    gemm_feats  <<<1024, 256, 0, stream>>>(X, wkt, feats_bf);       ck_launch("gemm_feats");
    feats32_emu2<<<8192, 256, 0, stream>>>(X, kern, feats32);       ck_launch("feats32_emu2");
    logits_emu  <<<1024, 256, 0, stream>>>(feats32, attn_s, attn_n, a_s32, a_n32);
                                                                    ck_launch("logits_emu");
    attn_emu    <<<512, 256, 0, stream>>>(A, feats_bf, a_s32, a_n32, biases, out0, view32);
                                                                    ck_launch("attn_emu");
    pool_emu    <<<8192, 256, 0, stream>>>(view32, pooled);         ck_launch("pool_emu");
    temp_emu    <<<8192, 256, 0, stream>>>(pooled, alpha, temp);    ck_launch("temp_emu");
    thresh_emu  <<<128, 128, 0, stream>>>(temp, thresh32);          ck_launch("thresh_emu");
    binarize_emu<<<8192, 256, 0, stream>>>(view32, thresh32, out1); ck_launch("binarize_emu");
}

// Round 2
// 960.193 us; speedup vs baseline: 4.5648x; 1.2463x over previous
//
#include <hip/hip_runtime.h>
#include <hip/hip_bf16.h>
#include <cstdio>
#include <math.h>

// GraphAttention forward, MI355X/gfx950.  Inputs/outputs FLOAT32.
// out0: bf16 MFMA path (PASSES at 2e-2).
// out1: EXACT numpy-fp32 emulation (established R4-R6: fp64 is not enough; the
// binary threshold decisions require bit-identical fp32):
//   - einsum sums (feats over f, logits over k, temp over j): SSE 4-lane 1-acc
//     dot, lane = idx%4, hsum ((a0+a1)+(a2+a3))
//   - np.sum reductions: numpy pairwise_sum, AVX512 base case
//   - exp/sigmoid: correctly-rounded fp32 via fp64 exp
//   - all fp32 ops via __f*_rn (no FMA contraction)
//
// R8 (this round): feats32_emu2 was L3-BW-bound: FETCH 1.7GB/dispatch (12x the
// 142MB footprint) because each (h,kg) slice re-read all of X (64x redundancy;
// X misses the 4MB/XCD L2). v3: block = 64 rows x 8 waves; lane=row, kg=waveId
// (readfirstlane -> provably uniform -> kern stays on scalar/SGPR path); X
// staged per-128f-chunk into LDS once per block and consumed by 8 waves x 2
// heads -> X redundancy 64x -> 4x. Per-output FADD/FMUL chain bit-identical.

typedef __attribute__((ext_vector_type(8))) short   s16x8;
typedef __attribute__((ext_vector_type(8))) __bf16  bf16x8;
typedef __attribute__((ext_vector_type(4))) float   fx4;

#define FADD __fadd_rn
#define FMUL __fmul_rn
#define FSUB __fsub_rn
#define FDIV __fdiv_rn
#define MASKC (-9999998976.0f)   // fl32(-1e10)

__device__ __forceinline__ fx4 mfma_bf16_16x16x32(s16x8 a, s16x8 b, fx4 c) {
    return __builtin_amdgcn_mfma_f32_16x16x32_bf16(
        __builtin_bit_cast(bf16x8, a), __builtin_bit_cast(bf16x8, b), c, 0, 0, 0);
}
__device__ __forceinline__ unsigned short f2bf(float f) {
    unsigned int x = __builtin_bit_cast(unsigned int, f);
    unsigned int lsb = (x >> 16) & 1u;
    x += 0x7fffu + lsb;
    return (unsigned short)(x >> 16);
}
__device__ __forceinline__ unsigned int pack2(float a, float b) {
    return (unsigned int)f2bf(a) | ((unsigned int)f2bf(b) << 16);
}
__device__ __forceinline__ float expf_cr(float x) {   // correctly-rounded expf
    return (float)exp((double)x);
}

// numpy pairwise_sum base (n=128), AVX512 flavor.
__device__ float pw128(const float* a) {
    float c[16];
#pragma unroll
    for (int l = 0; l < 16; ++l) {
        float t0 = FADD(FADD(a[l], a[16 + l]), FADD(a[32 + l], a[48 + l]));
        float t1 = FADD(FADD(a[64 + l], a[80 + l]), FADD(a[96 + l], a[112 + l]));
        c[l] = FADD(t0, t1);
    }
    float d[8], e[4], f[2];
#pragma unroll
    for (int l = 0; l < 8; ++l) d[l] = FADD(c[l], c[l + 8]);
#pragma unroll
    for (int l = 0; l < 4; ++l) e[l] = FADD(d[l], d[l + 4]);
#pragma unroll
    for (int l = 0; l < 2; ++l) f[l] = FADD(e[l], e[l + 2]);
    return FADD(f[0], f[1]);
}

// ---------------------------------------------------------------- out0 support
__global__ __launch_bounds__(256) void repack_w(const float* __restrict__ kern,
                                                unsigned short* __restrict__ wkt) {
    int t = blockIdx.x * 256 + threadIdx.x;
    int n = t >> 9, f = t & 511;
    int h = n >> 6, k = n & 63;
    wkt[t] = f2bf(kern[(h * 512 + f) * 64 + k]);
}

#define BK 32
__global__ __launch_bounds__(256) void gemm_feats(const float* __restrict__ X,
                                                  const unsigned short* __restrict__ Wkt,
                                                  unsigned short* __restrict__ feats_bf) {
    __shared__ alignas(16) unsigned short As[128 * BK];
    __shared__ alignas(16) unsigned short Bs[128 * BK];
    const int tid = threadIdx.x;
    const int mb = blockIdx.x >> 2, nb = blockIdx.x & 3;
    const int m0 = mb * 128, n0 = nb * 128;
    const int w = tid >> 6, lane = tid & 63;
    const int mw = (w & 1) * 64, nw = (w >> 1) * 64;
    const int lr = lane & 15, lq = lane >> 4;
    const int srow = tid >> 2, scol = (tid & 3) * 8;

    fx4 acc[4][4] = {};
    for (int k0 = 0; k0 < 512; k0 += BK) {
        __syncthreads();
        {
            const float* xr0 = &X[(m0 + srow) * 512 + k0 + scol];
            const float* xr1 = &X[(m0 + srow + 64) * 512 + k0 + scol];
            float4 a0 = *(const float4*)xr0, a1 = *(const float4*)(xr0 + 4);
            float4 b0 = *(const float4*)xr1, b1 = *(const float4*)(xr1 + 4);
            uint4 p0 = { pack2(a0.x, a0.y), pack2(a0.z, a0.w), pack2(a1.x, a1.y), pack2(a1.z, a1.w) };
            uint4 p1 = { pack2(b0.x, b0.y), pack2(b0.z, b0.w), pack2(b1.x, b1.y), pack2(b1.z, b1.w) };
            *(uint4*)&As[srow * BK + scol]        = p0;
            *(uint4*)&As[(srow + 64) * BK + scol] = p1;
            *(uint4*)&Bs[srow * BK + scol]        = *(const uint4*)&Wkt[(n0 + srow) * 512 + k0 + scol];
            *(uint4*)&Bs[(srow + 64) * BK + scol] = *(const uint4*)&Wkt[(n0 + srow + 64) * 512 + k0 + scol];
        }
        __syncthreads();
        s16x8 a[4], bb[4];
#pragma unroll
        for (int i = 0; i < 4; ++i) a[i]  = *(const s16x8*)&As[(mw + i * 16 + lr) * BK + lq * 8];
#pragma unroll
        for (int i = 0; i < 4; ++i) bb[i] = *(const s16x8*)&Bs[(nw + i * 16 + lr) * BK + lq * 8];
#pragma unroll
        for (int i = 0; i < 4; ++i)
#pragma unroll
            for (int j = 0; j < 4; ++j)
                acc[i][j] = mfma_bf16_16x16x32(a[i], bb[j], acc[i][j]);
    }
#pragma unroll
    for (int i = 0; i < 4; ++i)
#pragma unroll
        for (int j = 0; j < 4; ++j) {
            int col  = n0 + nw + j * 16 + lr;
            int rowb = m0 + mw + i * 16 + lq * 4;
#pragma unroll
            for (int r = 0; r < 4; ++r)
                feats_bf[(rowb + r) * 512 + col] = f2bf(acc[i][j][r]);
        }
}

// ---------------------------------------------------------------- feats32 (np emu, v3)
// feats32[h][row][k] = SSE-dot over f: lane = f%4, acc_l += x*w (order f, f+4), hsum.
// Block: 512 threads = 8 waves. lane = row (64 rows/block), kg = wave id
// (readfirstlane -> wave-uniform kern address -> scalar loads). X staged into
// LDS per 128-f chunk, read once per block, consumed by 8 waves x 2 heads.
// Per-output arithmetic sequence identical to v1/v2.
#define FCH 128
#define XS_STRIDE 132   // floats; 16B-aligned, uniform bank-group spread
__global__ __launch_bounds__(512) void feats32_emu3(const float* __restrict__ X,
                                                    const float* __restrict__ kern,
                                                    float* __restrict__ feats32) {
    __shared__ alignas(16) float Xs[64 * XS_STRIDE];   // 33,792 B
    const int tid = threadIdx.x;
    const int hg = blockIdx.x >> 9;          // 0..3  (grid = 4 * 512)
    const int rb = blockIdx.x & 511;         // 0..511
    const int h0 = hg * 2;
    const int lane = tid & 63;
    const int kg = __builtin_amdgcn_readfirstlane(tid >> 6);   // wave-uniform 0..7
    const int k0 = kg * 8;
    const int row0 = rb * 64;
    const int srow = tid >> 3, sseg = tid & 7;   // staging map: 64 rows x 8 segs

    float acc[2][8][4];
#pragma unroll
    for (int hh = 0; hh < 2; ++hh)
#pragma unroll
        for (int q = 0; q < 8; ++q)
#pragma unroll
            for (int l = 0; l < 4; ++l) acc[hh][q][l] = 0.f;

    for (int fc = 0; fc < 512; fc += FCH) {
        __syncthreads();
        {
            const float* gp = &X[(row0 + srow) * 512 + fc + sseg * 16];
            float* sp = &Xs[srow * XS_STRIDE + sseg * 16];
#pragma unroll
            for (int i = 0; i < 4; ++i)
                *(float4*)&sp[i * 4] = *(const float4*)&gp[i * 4];
        }
        __syncthreads();

        const float* __restrict__ xrow = &Xs[lane * XS_STRIDE];
#pragma unroll
        for (int hh = 0; hh < 2; ++hh) {
            const float* __restrict__ kp = &kern[((h0 + hh) * 512 + fc) * 64 + k0];
            for (int fo = 0; fo < FCH; fo += 8) {
                float xv[8];
                {
                    float4 xa = *(const float4*)&xrow[fo];
                    float4 xb = *(const float4*)&xrow[fo + 4];
                    xv[0] = xa.x; xv[1] = xa.y; xv[2] = xa.z; xv[3] = xa.w;
                    xv[4] = xb.x; xv[5] = xb.y; xv[6] = xb.z; xv[7] = xb.w;
                }
                float w[8][8];
#pragma unroll
                for (int j = 0; j < 8; ++j) {
                    float4 lo = *(const float4*)&kp[(fo + j) * 64];
                    float4 hi = *(const float4*)&kp[(fo + j) * 64 + 4];
                    w[j][0] = lo.x; w[j][1] = lo.y; w[j][2] = lo.z; w[j][3] = lo.w;
                    w[j][4] = hi.x; w[j][5] = hi.y; w[j][6] = hi.z; w[j][7] = hi.w;
                }
#pragma unroll
                for (int q = 0; q < 8; ++q) {
                    acc[hh][q][0] = FADD(acc[hh][q][0], FMUL(xv[0], w[0][q]));
                    acc[hh][q][1] = FADD(acc[hh][q][1], FMUL(xv[1], w[1][q]));
                    acc[hh][q][2] = FADD(acc[hh][q][2], FMUL(xv[2], w[2][q]));
                    acc[hh][q][3] = FADD(acc[hh][q][3], FMUL(xv[3], w[3][q]));
                    acc[hh][q][0] = FADD(acc[hh][q][0], FMUL(xv[4], w[4][q]));
                    acc[hh][q][1] = FADD(acc[hh][q][1], FMUL(xv[5], w[5][q]));
                    acc[hh][q][2] = FADD(acc[hh][q][2], FMUL(xv[6], w[6][q]));
                    acc[hh][q][3] = FADD(acc[hh][q][3], FMUL(xv[7], w[7][q]));
                }
            }
        }
    }

#pragma unroll
    for (int hh = 0; hh < 2; ++hh) {
        float* __restrict__ op = &feats32[((h0 + hh) * 32768 + row0 + lane) * 64 + k0];
        float4 o0, o1;
        o0.x = FADD(FADD(acc[hh][0][0], acc[hh][0][1]), FADD(acc[hh][0][2], acc[hh][0][3]));
        o0.y = FADD(FADD(acc[hh][1][0], acc[hh][1][1]), FADD(acc[hh][1][2], acc[hh][1][3]));
        o0.z = FADD(FADD(acc[hh][2][0], acc[hh][2][1]), FADD(acc[hh][2][2], acc[hh][2][3]));
        o0.w = FADD(FADD(acc[hh][3][0], acc[hh][3][1]), FADD(acc[hh][3][2], acc[hh][3][3]));
        o1.x = FADD(FADD(acc[hh][4][0], acc[hh][4][1]), FADD(acc[hh][4][2], acc[hh][4][3]));
        o1.y = FADD(FADD(acc[hh][5][0], acc[hh][5][1]), FADD(acc[hh][5][2], acc[hh][5][3]));
        o1.z = FADD(FADD(acc[hh][6][0], acc[hh][6][1]), FADD(acc[hh][6][2], acc[hh][6][3]));
        o1.w = FADD(FADD(acc[hh][7][0], acc[hh][7][1]), FADD(acc[hh][7][2], acc[hh][7][3]));
        *(float4*)&op[0] = o0;
        *(float4*)&op[4] = o1;
    }
}

// ---------------------------------------------------------------- logits (np emu)
__device__ float sse_dot64(const float* __restrict__ x, const float* __restrict__ y) {
    float a0 = 0.f, a1 = 0.f, a2 = 0.f, a3 = 0.f;
    for (int i = 0; i < 64; i += 8) {
        a0 = FADD(a0, FMUL(x[i + 0], y[i + 0]));
        a1 = FADD(a1, FMUL(x[i + 1], y[i + 1]));
        a2 = FADD(a2, FMUL(x[i + 2], y[i + 2]));
        a3 = FADD(a3, FMUL(x[i + 3], y[i + 3]));
        a0 = FADD(a0, FMUL(x[i + 4], y[i + 4]));
        a1 = FADD(a1, FMUL(x[i + 5], y[i + 5]));
        a2 = FADD(a2, FMUL(x[i + 6], y[i + 6]));
        a3 = FADD(a3, FMUL(x[i + 7], y[i + 7]));
    }
    return FADD(FADD(a0, a1), FADD(a2, a3));
}

__global__ __launch_bounds__(256) void logits_emu(const float* __restrict__ feats32,
                                                  const float* __restrict__ attn_s,
                                                  const float* __restrict__ attn_n,
                                                  float* __restrict__ a_s32,
                                                  float* __restrict__ a_n32) {
    int t = blockIdx.x * 256 + threadIdx.x;      // 262,144
    int row = t & 32767, h = t >> 15;
    const float* fr = &feats32[(h * 32768 + row) * 64];
    a_s32[h * 32768 + row] = sse_dot64(fr, &attn_s[h * 64]);
    a_n32[h * 32768 + row] = sse_dot64(fr, &attn_n[h * 64]);
}

// ---------------------------------------------------------------- attention (np-fp32 emu)
#define VT_STRIDE 264
#define AS_STRIDE 264
__global__ __launch_bounds__(256) void attn_emu(const float* __restrict__ A,
                                                const unsigned short* __restrict__ feats_bf,
                                                const float* __restrict__ a_s32,
                                                const float* __restrict__ a_n32,
                                                const float* __restrict__ biases,
                                                float* __restrict__ out0,
                                                float* __restrict__ view32) {
    __shared__ alignas(16) unsigned short Vt[64 * VT_STRIDE];   // 33792 B
    __shared__ alignas(4)  unsigned char  Asm[64 * AS_STRIDE];  // 16896 B
    __shared__ float an_l[8][256];                              //  8192 B
    __shared__ float as_l[8][64];                               //  2048 B
    __shared__ float Msh[8][64];                                //  2048 B
    __shared__ float Ssh[8][64];                                //  2048 B  = 65024 B

    const int tid = threadIdx.x;
    const int b = blockIdx.x >> 2;
    const int row0 = (blockIdx.x & 3) * 64;
    const int w = tid >> 6, lane = tid & 63;
    const int m = lane & 15, jq = lane >> 4;

    // stage adjacency as bytes
#pragma unroll
    for (int l = 0; l < 16; ++l) {
        int lin = tid + l * 256;
        int i = lin >> 6, jf = lin & 63;
        float4 av = *(const float4*)&A[(((b << 8) + row0 + i) << 8) + jf * 4];
        unsigned int bits = (av.x != 0.f ? 1u : 0u) | (av.y != 0.f ? 0x100u : 0u) |
                            (av.z != 0.f ? 0x10000u : 0u) | (av.w != 0.f ? 0x1000000u : 0u);
        *(unsigned int*)&Asm[i * AS_STRIDE + jf * 4] = bits;
    }
    // stage logits (all heads)
    for (int idx = tid; idx < 2048; idx += 256) {
        int h = idx >> 8, j = idx & 255;
        an_l[h][j] = a_n32[h * 32768 + (b << 8) + j];
    }
    for (int idx = tid; idx < 512; idx += 256) {
        int h = idx >> 6, i = idx & 63;
        as_l[h][i] = a_s32[h * 32768 + (b << 8) + row0 + i];
    }
    __syncthreads();

    // Phase A: per (i, h) task — np-fp32 M and pairwise-S
#pragma unroll
    for (int rep = 0; rep < 2; ++rep) {
        int task = tid + rep * 256;              // 0..511
        int i = task & 63, h = task >> 6;
        float asv = as_l[h][i];
        const unsigned char* arow = &Asm[i * AS_STRIDE];
        float M = -3.4e38f;
        for (int j = 0; j < 256; ++j) {
            float lg = FADD(asv, an_l[h][j]);
            float lr = lg > 0.f ? lg : FMUL(0.2f, lg);
            float v  = arow[j] ? lr : FADD(lr, MASKC);
            M = fmaxf(M, v);
        }
        float S = 0.f;
#pragma unroll
        for (int blk = 0; blk < 2; ++blk) {
            int j0 = blk * 128;
            float c[16];
#pragma unroll
            for (int l = 0; l < 16; ++l) {
                float ev[8];
#pragma unroll
                for (int q = 0; q < 8; ++q) {
                    int j = j0 + q * 16 + l;
                    float lg = FADD(asv, an_l[h][j]);
                    float lr = lg > 0.f ? lg : FMUL(0.2f, lg);
                    float v  = arow[j] ? lr : FADD(lr, MASKC);
                    ev[q] = expf_cr(FSUB(v, M));
                }
                float t0 = FADD(FADD(ev[0], ev[1]), FADD(ev[2], ev[3]));
                float t1 = FADD(FADD(ev[4], ev[5]), FADD(ev[6], ev[7]));
                c[l] = FADD(t0, t1);
            }
            float d[8], e4[4], f2[2];
#pragma unroll
            for (int l = 0; l < 8; ++l) d[l] = FADD(c[l], c[l + 8]);
#pragma unroll
            for (int l = 0; l < 4; ++l) e4[l] = FADD(d[l], d[l + 4]);
#pragma unroll
            for (int l = 0; l < 2; ++l) f2[l] = FADD(e4[l], e4[l + 2]);
            float blkS = FADD(f2[0], f2[1]);
            S = (blk == 0) ? blkS : FADD(S, blkS);
        }
        Msh[h][i] = M;
        Ssh[h][i] = S;
    }
    __syncthreads();

    // Phase B: per head — p (np-fp32), view accumulate, PV MFMA for out0
    float view_acc[8][8] = {};
    const int myrow = row0 + w * 16 + m;
    const int i_ln = w * 16 + m;
    const unsigned char* arow = &Asm[i_ln * AS_STRIDE];

    for (int h = 0; h < 8; ++h) {
        __syncthreads();
        {
            int kk = lane, jb = w;
            for (int it = 0; it < 64; ++it) {
                int j = jb * 64 + it;
                Vt[kk * VT_STRIDE + j] = feats_bf[(((b << 8) + j) << 9) + (h << 6) + kk];
            }
        }
        __syncthreads();

        float asv = as_l[h][i_ln];
        float Mi = Msh[h][i_ln];
        float Si = Ssh[h][i_ln];

        s16x8 pfrag[8];
#pragma unroll
        for (int kb = 0; kb < 8; ++kb) {
            int jbase = kb * 32 + jq * 8;
            s16x8 pf;
#pragma unroll
            for (int t = 0; t < 8; ++t) {
                int j = jbase + t;
                float lg = FADD(asv, an_l[h][j]);
                float lr = lg > 0.f ? lg : FMUL(0.2f, lg);
                float v  = arow[j] ? lr : FADD(lr, MASKC);
                float e  = expf_cr(FSUB(v, Mi));
                float p  = FDIV(e, Si);
                view_acc[kb][t] = FADD(view_acc[kb][t], FMUL(p, 0.125f));
                pf[t] = (short)f2bf(p);
            }
            pfrag[kb] = pf;
        }

        fx4 acc[4] = {};
#pragma unroll
        for (int kb = 0; kb < 8; ++kb) {
            int jo = kb * 32 + jq * 8;
#pragma unroll
            for (int nf = 0; nf < 4; ++nf) {
                s16x8 vf = *(const s16x8*)&Vt[(nf * 16 + m) * VT_STRIDE + jo];
                acc[nf] = mfma_bf16_16x16x32(pfrag[kb], vf, acc[nf]);
            }
        }
#pragma unroll
        for (int nf = 0; nf < 4; ++nf) {
            float bias = biases[h * 64 + nf * 16 + m];
#pragma unroll
            for (int r = 0; r < 4; ++r) {
                float val = acc[nf][r] + bias;
                val = val > 0.f ? val : 0.f;
                int gi = (b << 8) + row0 + w * 16 + jq * 4 + r;
                out0[gi * 512 + h * 64 + nf * 16 + m] = val;
            }
        }
    }

#pragma unroll
    for (int kb = 0; kb < 8; ++kb) {
        int base = (((b << 8) + myrow) << 8) + kb * 32 + jq * 8;
        float4 v0, v1;
        v0.x = view_acc[kb][0]; v0.y = view_acc[kb][1]; v0.z = view_acc[kb][2]; v0.w = view_acc[kb][3];
        v1.x = view_acc[kb][4]; v1.y = view_acc[kb][5]; v1.z = view_acc[kb][6]; v1.w = view_acc[kb][7];
        *(float4*)&view32[base]     = v0;
        *(float4*)&view32[base + 4] = v1;
    }
}

// ---------------------------------------------------------------- pool / temp / thresh
__global__ __launch_bounds__(256) void pool_emu(const float* __restrict__ view32,
                                                float* __restrict__ pooled) {
    int t = blockIdx.x * 256 + threadIdx.x;      // 2,097,152
    int j = t & 127, i = (t >> 7) & 127, b = t >> 14;
    const float* p = &view32[(b << 16) + (2 * i) * 256 + 2 * j];
    pooled[t] = fmaxf(fmaxf(p[0], p[1]), fmaxf(p[256], p[257]));
}

// temp[b,i,k] = SSE dot over j=0..127: pooled row (contig) x alpha[:,k] (stride 128)
__global__ __launch_bounds__(256) void temp_emu(const float* __restrict__ pooled,
                                                const float* __restrict__ alpha,
                                                float* __restrict__ temp) {
    int t = blockIdx.x * 256 + threadIdx.x;      // 2,097,152
    int k = t & 127, i = (t >> 7) & 127, b = t >> 14;
    const float* pr = &pooled[(b << 14) + i * 128];
    const float* ap = &alpha[k];                  // stride 128 over j
    float a0 = 0.f, a1 = 0.f, a2 = 0.f, a3 = 0.f;
    for (int j = 0; j < 128; j += 8) {
        a0 = FADD(a0, FMUL(pr[j + 0], ap[(j + 0) * 128]));
        a1 = FADD(a1, FMUL(pr[j + 1], ap[(j + 1) * 128]));
        a2 = FADD(a2, FMUL(pr[j + 2], ap[(j + 2) * 128]));
        a3 = FADD(a3, FMUL(pr[j + 3], ap[(j + 3) * 128]));
        a0 = FADD(a0, FMUL(pr[j + 4], ap[(j + 4) * 128]));
        a1 = FADD(a1, FMUL(pr[j + 5], ap[(j + 5) * 128]));
        a2 = FADD(a2, FMUL(pr[j + 6], ap[(j + 6) * 128]));
        a3 = FADD(a3, FMUL(pr[j + 7], ap[(j + 7) * 128]));
    }
    temp[t] = FADD(FADD(a0, a1), FADD(a2, a3));
}

// s[b] = numpy pairwise over 16384 (128 leaves of pw128, balanced binary tree)
__global__ __launch_bounds__(128) void thresh_emu(const float* __restrict__ temp,
                                                  float* __restrict__ thresh32) {
    __shared__ float red[128];
    int l = threadIdx.x, b = blockIdx.x;
    red[l] = pw128(&temp[(b << 14) + l * 128]);
    __syncthreads();
    for (int s = 64; s >= 1; s >>= 1) {
        float v = 0.f;
        if (l < s) v = FADD(red[2 * l], red[2 * l + 1]);
        __syncthreads();
        if (l < s) red[l] = v;
        __syncthreads();
    }
    if (l == 0) {
        float sfin = red[0];
        float e = expf_cr(-sfin);                 // np.exp(-s) fp32 (correctly rounded)
        thresh32[b] = FDIV(1.0f, FADD(1.0f, e)); // 1/(1+e)
    }
}

// ---------------------------------------------------------------- binarize (fp32)
__global__ __launch_bounds__(256) void binarize_emu(const float* __restrict__ view32,
                                                    const float* __restrict__ thresh32,
                                                    float* __restrict__ out1) {
    int g = blockIdx.x * 256 + threadIdx.x;
    int e = g * 4;
    int b = e >> 16, i = (e >> 8) & 255, j = e & 255;
    float th = thresh32[b];
    float4 v = *(const float4*)&view32[e];
    float4 o;
    o.x = (FADD(v.x, (i == j + 0) ? 1.f : 0.f) < th) ? 1.f : 0.f;
    o.y = (FADD(v.y, (i == j + 1) ? 1.f : 0.f) < th) ? 1.f : 0.f;
    o.z = (FADD(v.z, (i == j + 2) ? 1.f : 0.f) < th) ? 1.f : 0.f;
    o.w = (FADD(v.w, (i == j + 3) ? 1.f : 0.f) < th) ? 1.f : 0.f;
    *(float4*)&out1[e] = o;
}

// ---------------------------------------------------------------- launch
static inline void ck_launch(const char* name) {
    hipError_t e = hipGetLastError();
    if (e != hipSuccess)
        fprintf(stderr, "[gat] %s launch error %d: %s\n", name, (int)e, hipGetErrorString(e));
}

extern "C" void kernel_launch(void* const* d_in, const int* in_sizes, int n_in,
                              void* d_out, int out_size, void* d_ws, size_t ws_size,
                              hipStream_t stream) {
    const float* X      = (const float*)d_in[0];
    const float* A      = (const float*)d_in[1];
    const float* kern   = (const float*)d_in[2];
    const float* biases = (const float*)d_in[3];
    const float* attn_s = (const float*)d_in[4];
    const float* attn_n = (const float*)d_in[5];
    const float* alpha  = (const float*)d_in[6];

    char* ws = (char*)d_ws;
    unsigned short* feats_bf = (unsigned short*)(ws);             //  33,554,432 B
    float*          feats32  = (float*)(ws + 33554432);           //  67,108,864 B
    float*          view32   = (float*)(ws + 100663296);          //  33,554,432 B
    float*          a_s32    = (float*)(ws + 134217728);          //   1,048,576 B
    float*          a_n32    = (float*)(ws + 135266304);          //   1,048,576 B
    float*          pooled   = (float*)(ws + 136314880);          //   8,388,608 B
    float*          temp     = (float*)(ws + 144703488);          //   8,388,608 B
    float*          thresh32 = (float*)(ws + 153092096);          //         512 B
    unsigned short* wkt      = (unsigned short*)(ws + 153092608); //     524,288 B

    float* out0 = (float*)d_out;
    float* out1 = out0 + 16777216;

    repack_w    <<<1024, 256, 0, stream>>>(kern, wkt);              ck_launch("repack_w");
    gemm_feats  <<<1024, 256, 0, stream>>>(X, wkt, feats_bf);       ck_launch("gemm_feats");
    feats32_emu3<<<2048, 512, 0, stream>>>(X, kern, feats32);       ck_launch("feats32_emu3");
    logits_emu  <<<1024, 256, 0, stream>>>(feats32, attn_s, attn_n, a_s32, a_n32);
                                                                    ck_launch("logits_emu");
    attn_emu    <<<512, 256, 0, stream>>>(A, feats_bf, a_s32, a_n32, biases, out0, view32);
                                                                    ck_launch("attn_emu");
    pool_emu    <<<8192, 256, 0, stream>>>(view32, pooled);         ck_launch("pool_emu");
    temp_emu    <<<8192, 256, 0, stream>>>(pooled, alpha, temp);    ck_launch("temp_emu");
    thresh_emu  <<<128, 128, 0, stream>>>(temp, thresh32);          ck_launch("thresh_emu");
    binarize_emu<<<8192, 256, 0, stream>>>(view32, thresh32, out1); ck_launch("binarize_emu");
}

// Round 3
// 802.901 us; speedup vs baseline: 5.4591x; 1.1959x over previous
//
#include <hip/hip_runtime.h>
#include <hip/hip_bf16.h>
#include <cstdio>
#include <math.h>

// GraphAttention forward, MI355X/gfx950.  Inputs/outputs FLOAT32.
// out0: bf16 MFMA path (PASSES at 2e-2).
// out1: EXACT numpy-fp32 emulation (established R4-R6: fp64 is not enough; the
// binary threshold decisions require bit-identical fp32):
//   - einsum sums (feats over f, logits over k, temp over j): SSE 4-lane 1-acc
//     dot, lane = idx%4, hsum ((a0+a1)+(a2+a3))
//   - np.sum reductions: numpy pairwise_sum, AVX512 base case
//   - exp/sigmoid: correctly-rounded fp32 via fp64 exp
//   - all fp32 ops via __f*_rn (no FMA contraction)
//
// R9 (this round): feats32_emu3 at 414us vs ~218us VALU floor, VALUBusy 30% —
// lgkmcnt stalls on scalar weight loads (16 non-contiguous s_load_dwordx4 per
// 8-f group; 32KB/wave slice misses scalar L1 -> L2 latency). Fix: (a) repack
// kern fp32 to [h][kg][f][8k] so each 8-f weight group is 256B contiguous
// (4x s_load_dwordx16, sequential stream, 16KB slice scalar-cache resident);
// (b) loop interchange fo-outer/hh-inner halves xv LDS reads. kern_r aliased
// onto view32 region (dead until attn_emu). Per-output FADD/FMUL chains
// bit-identical (only independent-chain reordering + value relocation).

typedef __attribute__((ext_vector_type(8))) short   s16x8;
typedef __attribute__((ext_vector_type(8))) __bf16  bf16x8;
typedef __attribute__((ext_vector_type(4))) float   fx4;

#define FADD __fadd_rn
#define FMUL __fmul_rn
#define FSUB __fsub_rn
#define FDIV __fdiv_rn
#define MASKC (-9999998976.0f)   // fl32(-1e10)

__device__ __forceinline__ fx4 mfma_bf16_16x16x32(s16x8 a, s16x8 b, fx4 c) {
    return __builtin_amdgcn_mfma_f32_16x16x32_bf16(
        __builtin_bit_cast(bf16x8, a), __builtin_bit_cast(bf16x8, b), c, 0, 0, 0);
}
__device__ __forceinline__ unsigned short f2bf(float f) {
    unsigned int x = __builtin_bit_cast(unsigned int, f);
    unsigned int lsb = (x >> 16) & 1u;
    x += 0x7fffu + lsb;
    return (unsigned short)(x >> 16);
}
__device__ __forceinline__ unsigned int pack2(float a, float b) {
    return (unsigned int)f2bf(a) | ((unsigned int)f2bf(b) << 16);
}
__device__ __forceinline__ float expf_cr(float x) {   // correctly-rounded expf
    return (float)exp((double)x);
}

// numpy pairwise_sum base (n=128), AVX512 flavor.
__device__ float pw128(const float* a) {
    float c[16];
#pragma unroll
    for (int l = 0; l < 16; ++l) {
        float t0 = FADD(FADD(a[l], a[16 + l]), FADD(a[32 + l], a[48 + l]));
        float t1 = FADD(FADD(a[64 + l], a[80 + l]), FADD(a[96 + l], a[112 + l]));
        c[l] = FADD(t0, t1);
    }
    float d[8], e[4], f[2];
#pragma unroll
    for (int l = 0; l < 8; ++l) d[l] = FADD(c[l], c[l + 8]);
#pragma unroll
    for (int l = 0; l < 4; ++l) e[l] = FADD(d[l], d[l + 4]);
#pragma unroll
    for (int l = 0; l < 2; ++l) f[l] = FADD(e[l], e[l + 2]);
    return FADD(f[0], f[1]);
}

// ---------------------------------------------------------------- out0 support
__global__ __launch_bounds__(256) void repack_w(const float* __restrict__ kern,
                                                unsigned short* __restrict__ wkt) {
    int t = blockIdx.x * 256 + threadIdx.x;
    int n = t >> 9, f = t & 511;
    int h = n >> 6, k = n & 63;
    wkt[t] = f2bf(kern[(h * 512 + f) * 64 + k]);
}

// fp32 repack for feats32_emu4: kern_r[((h*8+kg)*512+f)*8 + kk]
__global__ __launch_bounds__(256) void repack_k32(const float* __restrict__ kern,
                                                  float* __restrict__ kern_r) {
    int t = blockIdx.x * 256 + threadIdx.x;      // 262,144
    int kk = t & 7, f = (t >> 3) & 511, kgh = t >> 12;
    int kg = kgh & 7, h = kgh >> 3;
    kern_r[t] = kern[(h * 512 + f) * 64 + kg * 8 + kk];
}

#define BK 32
__global__ __launch_bounds__(256) void gemm_feats(const float* __restrict__ X,
                                                  const unsigned short* __restrict__ Wkt,
                                                  unsigned short* __restrict__ feats_bf) {
    __shared__ alignas(16) unsigned short As[128 * BK];
    __shared__ alignas(16) unsigned short Bs[128 * BK];
    const int tid = threadIdx.x;
    const int mb = blockIdx.x >> 2, nb = blockIdx.x & 3;
    const int m0 = mb * 128, n0 = nb * 128;
    const int w = tid >> 6, lane = tid & 63;
    const int mw = (w & 1) * 64, nw = (w >> 1) * 64;
    const int lr = lane & 15, lq = lane >> 4;
    const int srow = tid >> 2, scol = (tid & 3) * 8;

    fx4 acc[4][4] = {};
    for (int k0 = 0; k0 < 512; k0 += BK) {
        __syncthreads();
        {
            const float* xr0 = &X[(m0 + srow) * 512 + k0 + scol];
            const float* xr1 = &X[(m0 + srow + 64) * 512 + k0 + scol];
            float4 a0 = *(const float4*)xr0, a1 = *(const float4*)(xr0 + 4);
            float4 b0 = *(const float4*)xr1, b1 = *(const float4*)(xr1 + 4);
            uint4 p0 = { pack2(a0.x, a0.y), pack2(a0.z, a0.w), pack2(a1.x, a1.y), pack2(a1.z, a1.w) };
            uint4 p1 = { pack2(b0.x, b0.y), pack2(b0.z, b0.w), pack2(b1.x, b1.y), pack2(b1.z, b1.w) };
            *(uint4*)&As[srow * BK + scol]        = p0;
            *(uint4*)&As[(srow + 64) * BK + scol] = p1;
            *(uint4*)&Bs[srow * BK + scol]        = *(const uint4*)&Wkt[(n0 + srow) * 512 + k0 + scol];
            *(uint4*)&Bs[(srow + 64) * BK + scol] = *(const uint4*)&Wkt[(n0 + srow + 64) * 512 + k0 + scol];
        }
        __syncthreads();
        s16x8 a[4], bb[4];
#pragma unroll
        for (int i = 0; i < 4; ++i) a[i]  = *(const s16x8*)&As[(mw + i * 16 + lr) * BK + lq * 8];
#pragma unroll
        for (int i = 0; i < 4; ++i) bb[i] = *(const s16x8*)&Bs[(nw + i * 16 + lr) * BK + lq * 8];
#pragma unroll
        for (int i = 0; i < 4; ++i)
#pragma unroll
            for (int j = 0; j < 4; ++j)
                acc[i][j] = mfma_bf16_16x16x32(a[i], bb[j], acc[i][j]);
    }
#pragma unroll
    for (int i = 0; i < 4; ++i)
#pragma unroll
        for (int j = 0; j < 4; ++j) {
            int col  = n0 + nw + j * 16 + lr;
            int rowb = m0 + mw + i * 16 + lq * 4;
#pragma unroll
            for (int r = 0; r < 4; ++r)
                feats_bf[(rowb + r) * 512 + col] = f2bf(acc[i][j][r]);
        }
}

// ---------------------------------------------------------------- feats32 (np emu, v4)
// feats32[h][row][k] = SSE-dot over f: lane = f%4, acc_l += x*w (order f, f+4), hsum.
// Block: 512 threads = 8 waves. lane = row, kg = wave id (readfirstlane ->
// wave-uniform -> scalar loads). X staged into LDS per 128-f chunk. Weights
// from kern_r [h][kg][f][8k]: each 8-f group is 256B contiguous -> wide s_load.
// fo-outer / hh-inner: xv read once per fo, used by both heads.
// Per-output arithmetic sequence identical to v1/v2/v3.
#define FCH 128
#define XS_STRIDE 132   // floats; 16B-aligned
__global__ __launch_bounds__(512) void feats32_emu4(const float* __restrict__ X,
                                                    const float* __restrict__ kern_r,
                                                    float* __restrict__ feats32) {
    __shared__ alignas(16) float Xs[64 * XS_STRIDE];   // 33,792 B
    const int tid = threadIdx.x;
    const int hg = blockIdx.x >> 9;          // 0..3  (grid = 4 * 512)
    const int rb = blockIdx.x & 511;         // 0..511
    const int h0 = hg * 2;
    const int lane = tid & 63;
    const int kg = __builtin_amdgcn_readfirstlane(tid >> 6);   // wave-uniform 0..7
    const int k0 = kg * 8;
    const int row0 = rb * 64;
    const int srow = tid >> 3, sseg = tid & 7;   // staging map: 64 rows x 8 segs

    float acc[2][8][4];
#pragma unroll
    for (int hh = 0; hh < 2; ++hh)
#pragma unroll
        for (int q = 0; q < 8; ++q)
#pragma unroll
            for (int l = 0; l < 4; ++l) acc[hh][q][l] = 0.f;

    // per-(h,kg) weight slices, 16KB each, contiguous
    const float* __restrict__ kp0 = &kern_r[(((h0 + 0) * 8 + kg) * 512) * 8];
    const float* __restrict__ kp1 = &kern_r[(((h0 + 1) * 8 + kg) * 512) * 8];

    for (int fc = 0; fc < 512; fc += FCH) {
        __syncthreads();
        {
            const float* gp = &X[(row0 + srow) * 512 + fc + sseg * 16];
            float* sp = &Xs[srow * XS_STRIDE + sseg * 16];
#pragma unroll
            for (int i = 0; i < 4; ++i)
                *(float4*)&sp[i * 4] = *(const float4*)&gp[i * 4];
        }
        __syncthreads();

        const float* __restrict__ xrow = &Xs[lane * XS_STRIDE];
        for (int fo = 0; fo < FCH; fo += 8) {
            float xv[8];
            {
                float4 xa = *(const float4*)&xrow[fo];
                float4 xb = *(const float4*)&xrow[fo + 4];
                xv[0] = xa.x; xv[1] = xa.y; xv[2] = xa.z; xv[3] = xa.w;
                xv[4] = xb.x; xv[5] = xb.y; xv[6] = xb.z; xv[7] = xb.w;
            }
#pragma unroll
            for (int hh = 0; hh < 2; ++hh) {
                const float* __restrict__ kp = (hh == 0 ? kp0 : kp1) + (fc + fo) * 8;
                float w[8][8];   // w[j][q] = kern[h][fc+fo+j][k0+q]; 256B contiguous
#pragma unroll
                for (int j = 0; j < 8; ++j) {
                    float4 lo = *(const float4*)&kp[j * 8];
                    float4 hi = *(const float4*)&kp[j * 8 + 4];
                    w[j][0] = lo.x; w[j][1] = lo.y; w[j][2] = lo.z; w[j][3] = lo.w;
                    w[j][4] = hi.x; w[j][5] = hi.y; w[j][6] = hi.z; w[j][7] = hi.w;
                }
#pragma unroll
                for (int q = 0; q < 8; ++q) {
                    acc[hh][q][0] = FADD(acc[hh][q][0], FMUL(xv[0], w[0][q]));
                    acc[hh][q][1] = FADD(acc[hh][q][1], FMUL(xv[1], w[1][q]));
                    acc[hh][q][2] = FADD(acc[hh][q][2], FMUL(xv[2], w[2][q]));
                    acc[hh][q][3] = FADD(acc[hh][q][3], FMUL(xv[3], w[3][q]));
                    acc[hh][q][0] = FADD(acc[hh][q][0], FMUL(xv[4], w[4][q]));
                    acc[hh][q][1] = FADD(acc[hh][q][1], FMUL(xv[5], w[5][q]));
                    acc[hh][q][2] = FADD(acc[hh][q][2], FMUL(xv[6], w[6][q]));
                    acc[hh][q][3] = FADD(acc[hh][q][3], FMUL(xv[7], w[7][q]));
                }
            }
        }
    }

#pragma unroll
    for (int hh = 0; hh < 2; ++hh) {
        float* __restrict__ op = &feats32[((h0 + hh) * 32768 + row0 + lane) * 64 + k0];
        float4 o0, o1;
        o0.x = FADD(FADD(acc[hh][0][0], acc[hh][0][1]), FADD(acc[hh][0][2], acc[hh][0][3]));
        o0.y = FADD(FADD(acc[hh][1][0], acc[hh][1][1]), FADD(acc[hh][1][2], acc[hh][1][3]));
        o0.z = FADD(FADD(acc[hh][2][0], acc[hh][2][1]), FADD(acc[hh][2][2], acc[hh][2][3]));
        o0.w = FADD(FADD(acc[hh][3][0], acc[hh][3][1]), FADD(acc[hh][3][2], acc[hh][3][3]));
        o1.x = FADD(FADD(acc[hh][4][0], acc[hh][4][1]), FADD(acc[hh][4][2], acc[hh][4][3]));
        o1.y = FADD(FADD(acc[hh][5][0], acc[hh][5][1]), FADD(acc[hh][5][2], acc[hh][5][3]));
        o1.z = FADD(FADD(acc[hh][6][0], acc[hh][6][1]), FADD(acc[hh][6][2], acc[hh][6][3]));
        o1.w = FADD(FADD(acc[hh][7][0], acc[hh][7][1]), FADD(acc[hh][7][2], acc[hh][7][3]));
        *(float4*)&op[0] = o0;
        *(float4*)&op[4] = o1;
    }
}

// ---------------------------------------------------------------- logits (np emu)
__device__ float sse_dot64(const float* __restrict__ x, const float* __restrict__ y) {
    float a0 = 0.f, a1 = 0.f, a2 = 0.f, a3 = 0.f;
    for (int i = 0; i < 64; i += 8) {
        a0 = FADD(a0, FMUL(x[i + 0], y[i + 0]));
        a1 = FADD(a1, FMUL(x[i + 1], y[i + 1]));
        a2 = FADD(a2, FMUL(x[i + 2], y[i + 2]));
        a3 = FADD(a3, FMUL(x[i + 3], y[i + 3]));
        a0 = FADD(a0, FMUL(x[i + 4], y[i + 4]));
        a1 = FADD(a1, FMUL(x[i + 5], y[i + 5]));
        a2 = FADD(a2, FMUL(x[i + 6], y[i + 6]));
        a3 = FADD(a3, FMUL(x[i + 7], y[i + 7]));
    }
    return FADD(FADD(a0, a1), FADD(a2, a3));
}

__global__ __launch_bounds__(256) void logits_emu(const float* __restrict__ feats32,
                                                  const float* __restrict__ attn_s,
                                                  const float* __restrict__ attn_n,
                                                  float* __restrict__ a_s32,
                                                  float* __restrict__ a_n32) {
    int t = blockIdx.x * 256 + threadIdx.x;      // 262,144
    int row = t & 32767, h = t >> 15;
    const float* fr = &feats32[(h * 32768 + row) * 64];
    a_s32[h * 32768 + row] = sse_dot64(fr, &attn_s[h * 64]);
    a_n32[h * 32768 + row] = sse_dot64(fr, &attn_n[h * 64]);
}

// ---------------------------------------------------------------- attention (np-fp32 emu)
#define VT_STRIDE 264
#define AS_STRIDE 264
__global__ __launch_bounds__(256) void attn_emu(const float* __restrict__ A,
                                                const unsigned short* __restrict__ feats_bf,
                                                const float* __restrict__ a_s32,
                                                const float* __restrict__ a_n32,
                                                const float* __restrict__ biases,
                                                float* __restrict__ out0,
                                                float* __restrict__ view32) {
    __shared__ alignas(16) unsigned short Vt[64 * VT_STRIDE];   // 33792 B
    __shared__ alignas(4)  unsigned char  Asm[64 * AS_STRIDE];  // 16896 B
    __shared__ float an_l[8][256];                              //  8192 B
    __shared__ float as_l[8][64];                               //  2048 B
    __shared__ float Msh[8][64];                                //  2048 B
    __shared__ float Ssh[8][64];                                //  2048 B  = 65024 B

    const int tid = threadIdx.x;
    const int b = blockIdx.x >> 2;
    const int row0 = (blockIdx.x & 3) * 64;
    const int w = tid >> 6, lane = tid & 63;
    const int m = lane & 15, jq = lane >> 4;

    // stage adjacency as bytes
#pragma unroll
    for (int l = 0; l < 16; ++l) {
        int lin = tid + l * 256;
        int i = lin >> 6, jf = lin & 63;
        float4 av = *(const float4*)&A[(((b << 8) + row0 + i) << 8) + jf * 4];
        unsigned int bits = (av.x != 0.f ? 1u : 0u) | (av.y != 0.f ? 0x100u : 0u) |
                            (av.z != 0.f ? 0x10000u : 0u) | (av.w != 0.f ? 0x1000000u : 0u);
        *(unsigned int*)&Asm[i * AS_STRIDE + jf * 4] = bits;
    }
    // stage logits (all heads)
    for (int idx = tid; idx < 2048; idx += 256) {
        int h = idx >> 8, j = idx & 255;
        an_l[h][j] = a_n32[h * 32768 + (b << 8) + j];
    }
    for (int idx = tid; idx < 512; idx += 256) {
        int h = idx >> 6, i = idx & 63;
        as_l[h][i] = a_s32[h * 32768 + (b << 8) + row0 + i];
    }
    __syncthreads();

    // Phase A: per (i, h) task — np-fp32 M and pairwise-S
#pragma unroll
    for (int rep = 0; rep < 2; ++rep) {
        int task = tid + rep * 256;              // 0..511
        int i = task & 63, h = task >> 6;
        float asv = as_l[h][i];
        const unsigned char* arow = &Asm[i * AS_STRIDE];
        float M = -3.4e38f;
        for (int j = 0; j < 256; ++j) {
            float lg = FADD(asv, an_l[h][j]);
            float lr = lg > 0.f ? lg : FMUL(0.2f, lg);
            float v  = arow[j] ? lr : FADD(lr, MASKC);
            M = fmaxf(M, v);
        }
        float S = 0.f;
#pragma unroll
        for (int blk = 0; blk < 2; ++blk) {
            int j0 = blk * 128;
            float c[16];
#pragma unroll
            for (int l = 0; l < 16; ++l) {
                float ev[8];
#pragma unroll
                for (int q = 0; q < 8; ++q) {
                    int j = j0 + q * 16 + l;
                    float lg = FADD(asv, an_l[h][j]);
                    float lr = lg > 0.f ? lg : FMUL(0.2f, lg);
                    float v  = arow[j] ? lr : FADD(lr, MASKC);
                    ev[q] = expf_cr(FSUB(v, M));
                }
                float t0 = FADD(FADD(ev[0], ev[1]), FADD(ev[2], ev[3]));
                float t1 = FADD(FADD(ev[4], ev[5]), FADD(ev[6], ev[7]));
                c[l] = FADD(t0, t1);
            }
            float d[8], e4[4], f2[2];
#pragma unroll
            for (int l = 0; l < 8; ++l) d[l] = FADD(c[l], c[l + 8]);
#pragma unroll
            for (int l = 0; l < 4; ++l) e4[l] = FADD(d[l], d[l + 4]);
#pragma unroll
            for (int l = 0; l < 2; ++l) f2[l] = FADD(e4[l], e4[l + 2]);
            float blkS = FADD(f2[0], f2[1]);
            S = (blk == 0) ? blkS : FADD(S, blkS);
        }
        Msh[h][i] = M;
        Ssh[h][i] = S;
    }
    __syncthreads();

    // Phase B: per head — p (np-fp32), view accumulate, PV MFMA for out0
    float view_acc[8][8] = {};
    const int myrow = row0 + w * 16 + m;
    const int i_ln = w * 16 + m;
    const unsigned char* arow = &Asm[i_ln * AS_STRIDE];

    for (int h = 0; h < 8; ++h) {
        __syncthreads();
        {
            int kk = lane, jb = w;
            for (int it = 0; it < 64; ++it) {
                int j = jb * 64 + it;
                Vt[kk * VT_STRIDE + j] = feats_bf[(((b << 8) + j) << 9) + (h << 6) + kk];
            }
        }
        __syncthreads();

        float asv = as_l[h][i_ln];
        float Mi = Msh[h][i_ln];
        float Si = Ssh[h][i_ln];

        s16x8 pfrag[8];
#pragma unroll
        for (int kb = 0; kb < 8; ++kb) {
            int jbase = kb * 32 + jq * 8;
            s16x8 pf;
#pragma unroll
            for (int t = 0; t < 8; ++t) {
                int j = jbase + t;
                float lg = FADD(asv, an_l[h][j]);
                float lr = lg > 0.f ? lg : FMUL(0.2f, lg);
                float v  = arow[j] ? lr : FADD(lr, MASKC);
                float e  = expf_cr(FSUB(v, Mi));
                float p  = FDIV(e, Si);
                view_acc[kb][t] = FADD(view_acc[kb][t], FMUL(p, 0.125f));
                pf[t] = (short)f2bf(p);
            }
            pfrag[kb] = pf;
        }

        fx4 acc[4] = {};
#pragma unroll
        for (int kb = 0; kb < 8; ++kb) {
            int jo = kb * 32 + jq * 8;
#pragma unroll
            for (int nf = 0; nf < 4; ++nf) {
                s16x8 vf = *(const s16x8*)&Vt[(nf * 16 + m) * VT_STRIDE + jo];
                acc[nf] = mfma_bf16_16x16x32(pfrag[kb], vf, acc[nf]);
            }
        }
#pragma unroll
        for (int nf = 0; nf < 4; ++nf) {
            float bias = biases[h * 64 + nf * 16 + m];
#pragma unroll
            for (int r = 0; r < 4; ++r) {
                float val = acc[nf][r] + bias;
                val = val > 0.f ? val : 0.f;
                int gi = (b << 8) + row0 + w * 16 + jq * 4 + r;
                out0[gi * 512 + h * 64 + nf * 16 + m] = val;
            }
        }
    }

#pragma unroll
    for (int kb = 0; kb < 8; ++kb) {
        int base = (((b << 8) + myrow) << 8) + kb * 32 + jq * 8;
        float4 v0, v1;
        v0.x = view_acc[kb][0]; v0.y = view_acc[kb][1]; v0.z = view_acc[kb][2]; v0.w = view_acc[kb][3];
        v1.x = view_acc[kb][4]; v1.y = view_acc[kb][5]; v1.z = view_acc[kb][6]; v1.w = view_acc[kb][7];
        *(float4*)&view32[base]     = v0;
        *(float4*)&view32[base + 4] = v1;
    }
}

// ---------------------------------------------------------------- pool / temp / thresh
__global__ __launch_bounds__(256) void pool_emu(const float* __restrict__ view32,
                                                float* __restrict__ pooled) {
    int t = blockIdx.x * 256 + threadIdx.x;      // 2,097,152
    int j = t & 127, i = (t >> 7) & 127, b = t >> 14;
    const float* p = &view32[(b << 16) + (2 * i) * 256 + 2 * j];
    pooled[t] = fmaxf(fmaxf(p[0], p[1]), fmaxf(p[256], p[257]));
}

// temp[b,i,k] = SSE dot over j=0..127: pooled row (contig) x alpha[:,k] (stride 128)
__global__ __launch_bounds__(256) void temp_emu(const float* __restrict__ pooled,
                                                const float* __restrict__ alpha,
                                                float* __restrict__ temp) {
    int t = blockIdx.x * 256 + threadIdx.x;      // 2,097,152
    int k = t & 127, i = (t >> 7) & 127, b = t >> 14;
    const float* pr = &pooled[(b << 14) + i * 128];
    const float* ap = &alpha[k];                  // stride 128 over j
    float a0 = 0.f, a1 = 0.f, a2 = 0.f, a3 = 0.f;
    for (int j = 0; j < 128; j += 8) {
        a0 = FADD(a0, FMUL(pr[j + 0], ap[(j + 0) * 128]));
        a1 = FADD(a1, FMUL(pr[j + 1], ap[(j + 1) * 128]));
        a2 = FADD(a2, FMUL(pr[j + 2], ap[(j + 2) * 128]));
        a3 = FADD(a3, FMUL(pr[j + 3], ap[(j + 3) * 128]));
        a0 = FADD(a0, FMUL(pr[j + 4], ap[(j + 4) * 128]));
        a1 = FADD(a1, FMUL(pr[j + 5], ap[(j + 5) * 128]));
        a2 = FADD(a2, FMUL(pr[j + 6], ap[(j + 6) * 128]));
        a3 = FADD(a3, FMUL(pr[j + 7], ap[(j + 7) * 128]));
    }
    temp[t] = FADD(FADD(a0, a1), FADD(a2, a3));
}

// s[b] = numpy pairwise over 16384 (128 leaves of pw128, balanced binary tree)
__global__ __launch_bounds__(128) void thresh_emu(const float* __restrict__ temp,
                                                  float* __restrict__ thresh32) {
    __shared__ float red[128];
    int l = threadIdx.x, b = blockIdx.x;
    red[l] = pw128(&temp[(b << 14) + l * 128]);
    __syncthreads();
    for (int s = 64; s >= 1; s >>= 1) {
        float v = 0.f;
        if (l < s) v = FADD(red[2 * l], red[2 * l + 1]);
        __syncthreads();
        if (l < s) red[l] = v;
        __syncthreads();
    }
    if (l == 0) {
        float sfin = red[0];
        float e = expf_cr(-sfin);                 // np.exp(-s) fp32 (correctly rounded)
        thresh32[b] = FDIV(1.0f, FADD(1.0f, e)); // 1/(1+e)
    }
}

// ---------------------------------------------------------------- binarize (fp32)
__global__ __launch_bounds__(256) void binarize_emu(const float* __restrict__ view32,
                                                    const float* __restrict__ thresh32,
                                                    float* __restrict__ out1) {
    int g = blockIdx.x * 256 + threadIdx.x;
    int e = g * 4;
    int b = e >> 16, i = (e >> 8) & 255, j = e & 255;
    float th = thresh32[b];
    float4 v = *(const float4*)&view32[e];
    float4 o;
    o.x = (FADD(v.x, (i == j + 0) ? 1.f : 0.f) < th) ? 1.f : 0.f;
    o.y = (FADD(v.y, (i == j + 1) ? 1.f : 0.f) < th) ? 1.f : 0.f;
    o.z = (FADD(v.z, (i == j + 2) ? 1.f : 0.f) < th) ? 1.f : 0.f;
    o.w = (FADD(v.w, (i == j + 3) ? 1.f : 0.f) < th) ? 1.f : 0.f;
    *(float4*)&out1[e] = o;
}

// ---------------------------------------------------------------- launch
static inline void ck_launch(const char* name) {
    hipError_t e = hipGetLastError();
    if (e != hipSuccess)
        fprintf(stderr, "[gat] %s launch error %d: %s\n", name, (int)e, hipGetErrorString(e));
}

extern "C" void kernel_launch(void* const* d_in, const int* in_sizes, int n_in,
                              void* d_out, int out_size, void* d_ws, size_t ws_size,
                              hipStream_t stream) {
    const float* X      = (const float*)d_in[0];
    const float* A      = (const float*)d_in[1];
    const float* kern   = (const float*)d_in[2];
    const float* biases = (const float*)d_in[3];
    const float* attn_s = (const float*)d_in[4];
    const float* attn_n = (const float*)d_in[5];
    const float* alpha  = (const float*)d_in[6];

    char* ws = (char*)d_ws;
    unsigned short* feats_bf = (unsigned short*)(ws);             //  33,554,432 B
    float*          feats32  = (float*)(ws + 33554432);           //  67,108,864 B
    float*          view32   = (float*)(ws + 100663296);          //  33,554,432 B
    float*          a_s32    = (float*)(ws + 134217728);          //   1,048,576 B
    float*          a_n32    = (float*)(ws + 135266304);          //   1,048,576 B
    float*          pooled   = (float*)(ws + 136314880);          //   8,388,608 B
    float*          temp     = (float*)(ws + 144703488);          //   8,388,608 B
    float*          thresh32 = (float*)(ws + 153092096);          //         512 B
    unsigned short* wkt      = (unsigned short*)(ws + 153092608); //     524,288 B

    // kern_r (8 MB) aliased onto view32's region: dead until attn_emu writes
    // view32, and feats32_emu4 (the only reader) runs strictly before that on
    // the same stream.
    float*          kern_r   = (float*)(ws + 100663296);

    float* out0 = (float*)d_out;
    float* out1 = out0 + 16777216;

    repack_w    <<<1024, 256, 0, stream>>>(kern, wkt);              ck_launch("repack_w");
    repack_k32  <<<1024, 256, 0, stream>>>(kern, kern_r);           ck_launch("repack_k32");
    gemm_feats  <<<1024, 256, 0, stream>>>(X, wkt, feats_bf);       ck_launch("gemm_feats");
    feats32_emu4<<<2048, 512, 0, stream>>>(X, kern_r, feats32);     ck_launch("feats32_emu4");
    logits_emu  <<<1024, 256, 0, stream>>>(feats32, attn_s, attn_n, a_s32, a_n32);
                                                                    ck_launch("logits_emu");
    attn_emu    <<<512, 256, 0, stream>>>(A, feats_bf, a_s32, a_n32, biases, out0, view32);
                                                                    ck_launch("attn_emu");
    pool_emu    <<<8192, 256, 0, stream>>>(view32, pooled);         ck_launch("pool_emu");
    temp_emu    <<<8192, 256, 0, stream>>>(pooled, alpha, temp);    ck_launch("temp_emu");
    thresh_emu  <<<128, 128, 0, stream>>>(temp, thresh32);          ck_launch("thresh_emu");
    binarize_emu<<<8192, 256, 0, stream>>>(view32, thresh32, out1); ck_launch("binarize_emu");
}

// Round 4
// 706.281 us; speedup vs baseline: 6.2059x; 1.1368x over previous
//
#include <hip/hip_runtime.h>
#include <hip/hip_bf16.h>
#include <cstdio>
#include <math.h>

// GraphAttention forward, MI355X/gfx950.  Inputs/outputs FLOAT32.
// out0: bf16 MFMA path (PASSES at 2e-2).
// out1: EXACT numpy-fp32 emulation (established R4-R6: fp64 is not enough; the
// binary threshold decisions require bit-identical fp32):
//   - einsum sums (feats over f, logits over k, temp over j): SSE 4-lane 1-acc
//     dot, lane = idx%4, hsum ((a0+a1)+(a2+a3))
//   - np.sum reductions: numpy pairwise_sum, AVX512 base case
//   - exp/sigmoid: correctly-rounded fp32 via fp64 exp
//   - all fp32 ops via __f*_rn (no FMA contraction)
//
// R10 (this round): attn_emu computed every exp TWICE (Phase A for S, Phase B
// for p) — 134M fp64-exp calls/dispatch, half redundant. New single-pass
// structure: the 4 lanes owning a row (jq=0..3) compute 64 logits each ONCE,
// M via order-free fmaxf shfl_xor(16/32), exp once into registers, S via a
// shuffle network reproducing numpy's pairwise tree EXACTLY (s1 = xor32 pair
// = (ev_q+ev_{q+1}); c = ((s1_0+s1_1)+(s1_2+s1_3)); d = xor16 pair = c[l]+
// c[l+8]; in-thread e4/f2 tail; FADD commutative -> identical bits in all
// lanes). Adjacency as 256-bit register bitmask (kills 4096 ds_read_u8/thr),
// an_l read as float4, Vt staged via 16B loads. LDS 65024->46080 B.

typedef __attribute__((ext_vector_type(8))) short   s16x8;
typedef __attribute__((ext_vector_type(8))) __bf16  bf16x8;
typedef __attribute__((ext_vector_type(4))) float   fx4;

#define FADD __fadd_rn
#define FMUL __fmul_rn
#define FSUB __fsub_rn
#define FDIV __fdiv_rn
#define MASKC (-9999998976.0f)   // fl32(-1e10)

__device__ __forceinline__ fx4 mfma_bf16_16x16x32(s16x8 a, s16x8 b, fx4 c) {
    return __builtin_amdgcn_mfma_f32_16x16x32_bf16(
        __builtin_bit_cast(bf16x8, a), __builtin_bit_cast(bf16x8, b), c, 0, 0, 0);
}
__device__ __forceinline__ unsigned short f2bf(float f) {
    unsigned int x = __builtin_bit_cast(unsigned int, f);
    unsigned int lsb = (x >> 16) & 1u;
    x += 0x7fffu + lsb;
    return (unsigned short)(x >> 16);
}
__device__ __forceinline__ unsigned int pack2(float a, float b) {
    return (unsigned int)f2bf(a) | ((unsigned int)f2bf(b) << 16);
}
__device__ __forceinline__ float expf_cr(float x) {   // correctly-rounded expf
    return (float)exp((double)x);
}

// numpy pairwise_sum base (n=128), AVX512 flavor.
__device__ float pw128(const float* a) {
    float c[16];
#pragma unroll
    for (int l = 0; l < 16; ++l) {
        float t0 = FADD(FADD(a[l], a[16 + l]), FADD(a[32 + l], a[48 + l]));
        float t1 = FADD(FADD(a[64 + l], a[80 + l]), FADD(a[96 + l], a[112 + l]));
        c[l] = FADD(t0, t1);
    }
    float d[8], e[4], f[2];
#pragma unroll
    for (int l = 0; l < 8; ++l) d[l] = FADD(c[l], c[l + 8]);
#pragma unroll
    for (int l = 0; l < 4; ++l) e[l] = FADD(d[l], d[l + 4]);
#pragma unroll
    for (int l = 0; l < 2; ++l) f[l] = FADD(e[l], e[l + 2]);
    return FADD(f[0], f[1]);
}

// ---------------------------------------------------------------- out0 support
__global__ __launch_bounds__(256) void repack_w(const float* __restrict__ kern,
                                                unsigned short* __restrict__ wkt) {
    int t = blockIdx.x * 256 + threadIdx.x;
    int n = t >> 9, f = t & 511;
    int h = n >> 6, k = n & 63;
    wkt[t] = f2bf(kern[(h * 512 + f) * 64 + k]);
}

// fp32 repack for feats32_emu4: kern_r[((h*8+kg)*512+f)*8 + kk]
__global__ __launch_bounds__(256) void repack_k32(const float* __restrict__ kern,
                                                  float* __restrict__ kern_r) {
    int t = blockIdx.x * 256 + threadIdx.x;      // 262,144
    int kk = t & 7, f = (t >> 3) & 511, kgh = t >> 12;
    int kg = kgh & 7, h = kgh >> 3;
    kern_r[t] = kern[(h * 512 + f) * 64 + kg * 8 + kk];
}

#define BK 32
__global__ __launch_bounds__(256) void gemm_feats(const float* __restrict__ X,
                                                  const unsigned short* __restrict__ Wkt,
                                                  unsigned short* __restrict__ feats_bf) {
    __shared__ alignas(16) unsigned short As[128 * BK];
    __shared__ alignas(16) unsigned short Bs[128 * BK];
    const int tid = threadIdx.x;
    const int mb = blockIdx.x >> 2, nb = blockIdx.x & 3;
    const int m0 = mb * 128, n0 = nb * 128;
    const int w = tid >> 6, lane = tid & 63;
    const int mw = (w & 1) * 64, nw = (w >> 1) * 64;
    const int lr = lane & 15, lq = lane >> 4;
    const int srow = tid >> 2, scol = (tid & 3) * 8;

    fx4 acc[4][4] = {};
    for (int k0 = 0; k0 < 512; k0 += BK) {
        __syncthreads();
        {
            const float* xr0 = &X[(m0 + srow) * 512 + k0 + scol];
            const float* xr1 = &X[(m0 + srow + 64) * 512 + k0 + scol];
            float4 a0 = *(const float4*)xr0, a1 = *(const float4*)(xr0 + 4);
            float4 b0 = *(const float4*)xr1, b1 = *(const float4*)(xr1 + 4);
            uint4 p0 = { pack2(a0.x, a0.y), pack2(a0.z, a0.w), pack2(a1.x, a1.y), pack2(a1.z, a1.w) };
            uint4 p1 = { pack2(b0.x, b0.y), pack2(b0.z, b0.w), pack2(b1.x, b1.y), pack2(b1.z, b1.w) };
            *(uint4*)&As[srow * BK + scol]        = p0;
            *(uint4*)&As[(srow + 64) * BK + scol] = p1;
            *(uint4*)&Bs[srow * BK + scol]        = *(const uint4*)&Wkt[(n0 + srow) * 512 + k0 + scol];
            *(uint4*)&Bs[(srow + 64) * BK + scol] = *(const uint4*)&Wkt[(n0 + srow + 64) * 512 + k0 + scol];
        }
        __syncthreads();
        s16x8 a[4], bb[4];
#pragma unroll
        for (int i = 0; i < 4; ++i) a[i]  = *(const s16x8*)&As[(mw + i * 16 + lr) * BK + lq * 8];
#pragma unroll
        for (int i = 0; i < 4; ++i) bb[i] = *(const s16x8*)&Bs[(nw + i * 16 + lr) * BK + lq * 8];
#pragma unroll
        for (int i = 0; i < 4; ++i)
#pragma unroll
            for (int j = 0; j < 4; ++j)
                acc[i][j] = mfma_bf16_16x16x32(a[i], bb[j], acc[i][j]);
    }
#pragma unroll
    for (int i = 0; i < 4; ++i)
#pragma unroll
        for (int j = 0; j < 4; ++j) {
            int col  = n0 + nw + j * 16 + lr;
            int rowb = m0 + mw + i * 16 + lq * 4;
#pragma unroll
            for (int r = 0; r < 4; ++r)
                feats_bf[(rowb + r) * 512 + col] = f2bf(acc[i][j][r]);
        }
}

// ---------------------------------------------------------------- feats32 (np emu, v4)
#define FCH 128
#define XS_STRIDE 132   // floats; 16B-aligned
__global__ __launch_bounds__(512) void feats32_emu4(const float* __restrict__ X,
                                                    const float* __restrict__ kern_r,
                                                    float* __restrict__ feats32) {
    __shared__ alignas(16) float Xs[64 * XS_STRIDE];   // 33,792 B
    const int tid = threadIdx.x;
    const int hg = blockIdx.x >> 9;          // 0..3  (grid = 4 * 512)
    const int rb = blockIdx.x & 511;         // 0..511
    const int h0 = hg * 2;
    const int lane = tid & 63;
    const int kg = __builtin_amdgcn_readfirstlane(tid >> 6);   // wave-uniform 0..7
    const int k0 = kg * 8;
    const int row0 = rb * 64;
    const int srow = tid >> 3, sseg = tid & 7;   // staging map: 64 rows x 8 segs

    float acc[2][8][4];
#pragma unroll
    for (int hh = 0; hh < 2; ++hh)
#pragma unroll
        for (int q = 0; q < 8; ++q)
#pragma unroll
            for (int l = 0; l < 4; ++l) acc[hh][q][l] = 0.f;

    // per-(h,kg) weight slices, 16KB each, contiguous
    const float* __restrict__ kp0 = &kern_r[(((h0 + 0) * 8 + kg) * 512) * 8];
    const float* __restrict__ kp1 = &kern_r[(((h0 + 1) * 8 + kg) * 512) * 8];

    for (int fc = 0; fc < 512; fc += FCH) {
        __syncthreads();
        {
            const float* gp = &X[(row0 + srow) * 512 + fc + sseg * 16];
            float* sp = &Xs[srow * XS_STRIDE + sseg * 16];
#pragma unroll
            for (int i = 0; i < 4; ++i)
                *(float4*)&sp[i * 4] = *(const float4*)&gp[i * 4];
        }
        __syncthreads();

        const float* __restrict__ xrow = &Xs[lane * XS_STRIDE];
        for (int fo = 0; fo < FCH; fo += 8) {
            float xv[8];
            {
                float4 xa = *(const float4*)&xrow[fo];
                float4 xb = *(const float4*)&xrow[fo + 4];
                xv[0] = xa.x; xv[1] = xa.y; xv[2] = xa.z; xv[3] = xa.w;
                xv[4] = xb.x; xv[5] = xb.y; xv[6] = xb.z; xv[7] = xb.w;
            }
#pragma unroll
            for (int hh = 0; hh < 2; ++hh) {
                const float* __restrict__ kp = (hh == 0 ? kp0 : kp1) + (fc + fo) * 8;
                float w[8][8];   // w[j][q] = kern[h][fc+fo+j][k0+q]; 256B contiguous
#pragma unroll
                for (int j = 0; j < 8; ++j) {
                    float4 lo = *(const float4*)&kp[j * 8];
                    float4 hi = *(const float4*)&kp[j * 8 + 4];
                    w[j][0] = lo.x; w[j][1] = lo.y; w[j][2] = lo.z; w[j][3] = lo.w;
                    w[j][4] = hi.x; w[j][5] = hi.y; w[j][6] = hi.z; w[j][7] = hi.w;
                }
#pragma unroll
                for (int q = 0; q < 8; ++q) {
                    acc[hh][q][0] = FADD(acc[hh][q][0], FMUL(xv[0], w[0][q]));
                    acc[hh][q][1] = FADD(acc[hh][q][1], FMUL(xv[1], w[1][q]));
                    acc[hh][q][2] = FADD(acc[hh][q][2], FMUL(xv[2], w[2][q]));
                    acc[hh][q][3] = FADD(acc[hh][q][3], FMUL(xv[3], w[3][q]));
                    acc[hh][q][0] = FADD(acc[hh][q][0], FMUL(xv[4], w[4][q]));
                    acc[hh][q][1] = FADD(acc[hh][q][1], FMUL(xv[5], w[5][q]));
                    acc[hh][q][2] = FADD(acc[hh][q][2], FMUL(xv[6], w[6][q]));
                    acc[hh][q][3] = FADD(acc[hh][q][3], FMUL(xv[7], w[7][q]));
                }
            }
        }
    }

#pragma unroll
    for (int hh = 0; hh < 2; ++hh) {
        float* __restrict__ op = &feats32[((h0 + hh) * 32768 + row0 + lane) * 64 + k0];
        float4 o0, o1;
        o0.x = FADD(FADD(acc[hh][0][0], acc[hh][0][1]), FADD(acc[hh][0][2], acc[hh][0][3]));
        o0.y = FADD(FADD(acc[hh][1][0], acc[hh][1][1]), FADD(acc[hh][1][2], acc[hh][1][3]));
        o0.z = FADD(FADD(acc[hh][2][0], acc[hh][2][1]), FADD(acc[hh][2][2], acc[hh][2][3]));
        o0.w = FADD(FADD(acc[hh][3][0], acc[hh][3][1]), FADD(acc[hh][3][2], acc[hh][3][3]));
        o1.x = FADD(FADD(acc[hh][4][0], acc[hh][4][1]), FADD(acc[hh][4][2], acc[hh][4][3]));
        o1.y = FADD(FADD(acc[hh][5][0], acc[hh][5][1]), FADD(acc[hh][5][2], acc[hh][5][3]));
        o1.z = FADD(FADD(acc[hh][6][0], acc[hh][6][1]), FADD(acc[hh][6][2], acc[hh][6][3]));
        o1.w = FADD(FADD(acc[hh][7][0], acc[hh][7][1]), FADD(acc[hh][7][2], acc[hh][7][3]));
        *(float4*)&op[0] = o0;
        *(float4*)&op[4] = o1;
    }
}

// ---------------------------------------------------------------- logits (np emu)
__device__ float sse_dot64(const float* __restrict__ x, const float* __restrict__ y) {
    float a0 = 0.f, a1 = 0.f, a2 = 0.f, a3 = 0.f;
    for (int i = 0; i < 64; i += 8) {
        a0 = FADD(a0, FMUL(x[i + 0], y[i + 0]));
        a1 = FADD(a1, FMUL(x[i + 1], y[i + 1]));
        a2 = FADD(a2, FMUL(x[i + 2], y[i + 2]));
        a3 = FADD(a3, FMUL(x[i + 3], y[i + 3]));
        a0 = FADD(a0, FMUL(x[i + 4], y[i + 4]));
        a1 = FADD(a1, FMUL(x[i + 5], y[i + 5]));
        a2 = FADD(a2, FMUL(x[i + 6], y[i + 6]));
        a3 = FADD(a3, FMUL(x[i + 7], y[i + 7]));
    }
    return FADD(FADD(a0, a1), FADD(a2, a3));
}

__global__ __launch_bounds__(256) void logits_emu(const float* __restrict__ feats32,
                                                  const float* __restrict__ attn_s,
                                                  const float* __restrict__ attn_n,
                                                  float* __restrict__ a_s32,
                                                  float* __restrict__ a_n32) {
    int t = blockIdx.x * 256 + threadIdx.x;      // 262,144
    int row = t & 32767, h = t >> 15;
    const float* fr = &feats32[(h * 32768 + row) * 64];
    a_s32[h * 32768 + row] = sse_dot64(fr, &attn_s[h * 64]);
    a_n32[h * 32768 + row] = sse_dot64(fr, &attn_n[h * 64]);
}

// ---------------------------------------------------------------- attention (np-fp32 emu, v2)
// Single-pass: per row (4 lanes jq=0..3), logits+exp computed ONCE; M by
// order-free fmax shuffles; S by shuffle network reproducing numpy's pairwise
// tree exactly (see header comment). Adjacency in register bitmask.
#define VT_STRIDE 264
__global__ __launch_bounds__(256) void attn_emu(const float* __restrict__ A,
                                                const unsigned short* __restrict__ feats_bf,
                                                const float* __restrict__ a_s32,
                                                const float* __restrict__ a_n32,
                                                const float* __restrict__ biases,
                                                float* __restrict__ out0,
                                                float* __restrict__ view32) {
    __shared__ alignas(16) unsigned short Vt[64 * VT_STRIDE];   // 33792 B
    __shared__ alignas(16) unsigned int   Abits[64][8];         //  2048 B
    __shared__ alignas(16) float an_l[8][256];                  //  8192 B
    __shared__ alignas(16) float as_l[8][64];                   //  2048 B  = 46080 B

    const int tid = threadIdx.x;
    const int b = blockIdx.x >> 2;
    const int row0 = (blockIdx.x & 3) * 64;
    const int w = tid >> 6, lane = tid & 63;
    const int m = lane & 15, jq = lane >> 4;

    // stage adjacency as bitmask: 64 rows x 256 bits
    {
        int i = tid >> 2, sg = tid & 3;
        const float* ar = &A[(((b << 8) + row0 + i) << 8) + sg * 64];
        unsigned int w0 = 0, w1 = 0;
#pragma unroll
        for (int q = 0; q < 8; ++q) {
            float4 av = *(const float4*)&ar[q * 4];
            unsigned int m4 = (av.x != 0.f ? 1u : 0u) | (av.y != 0.f ? 2u : 0u) |
                              (av.z != 0.f ? 4u : 0u) | (av.w != 0.f ? 8u : 0u);
            w0 |= m4 << (q * 4);
        }
#pragma unroll
        for (int q = 8; q < 16; ++q) {
            float4 av = *(const float4*)&ar[q * 4];
            unsigned int m4 = (av.x != 0.f ? 1u : 0u) | (av.y != 0.f ? 2u : 0u) |
                              (av.z != 0.f ? 4u : 0u) | (av.w != 0.f ? 8u : 0u);
            w1 |= m4 << ((q - 8) * 4);
        }
        Abits[i][sg * 2]     = w0;
        Abits[i][sg * 2 + 1] = w1;
    }
    // stage logits (all heads)
    for (int idx = tid; idx < 2048; idx += 256) {
        int h = idx >> 8, j = idx & 255;
        an_l[h][j] = a_n32[h * 32768 + (b << 8) + j];
    }
    for (int idx = tid; idx < 512; idx += 256) {
        int h = idx >> 6, i = idx & 63;
        as_l[h][i] = a_s32[h * 32768 + (b << 8) + row0 + i];
    }
    __syncthreads();

    const int i_ln = w * 16 + m;
    const int myrow = row0 + i_ln;
    unsigned int abits[8];
#pragma unroll
    for (int u = 0; u < 8; ++u) abits[u] = Abits[i_ln][u];

    float view_acc[8][8] = {};

    for (int h = 0; h < 8; ++h) {
        __syncthreads();
        {   // stage V^T for this head: 16B global loads, scalar LDS writes
            int jb = w;
#pragma unroll
            for (int it = 0; it < 8; ++it) {
                int j  = jb * 64 + it * 8 + (lane >> 3);
                int kg = lane & 7;
                s16x8 v8 = *(const s16x8*)&feats_bf[(((b << 8) + j) << 9) + (h << 6) + kg * 8];
#pragma unroll
                for (int u = 0; u < 8; ++u)
                    Vt[(kg * 8 + u) * VT_STRIDE + j] = (unsigned short)v8[u];
            }
        }
        __syncthreads();

        const float asv = as_l[h][i_ln];

        // ---- logits once, tracking local max
        float ev[8][8];
        float Mloc = -3.4e38f;
#pragma unroll
        for (int kb = 0; kb < 8; ++kb) {
            int jbase = kb * 32 + jq * 8;
            float4 an0 = *(const float4*)&an_l[h][jbase];
            float4 an1 = *(const float4*)&an_l[h][jbase + 4];
            float anv[8] = { an0.x, an0.y, an0.z, an0.w, an1.x, an1.y, an1.z, an1.w };
            unsigned int mb = (abits[kb] >> (jq * 8)) & 0xffu;
#pragma unroll
            for (int t = 0; t < 8; ++t) {
                float lg = FADD(asv, anv[t]);
                float lr = lg > 0.f ? lg : FMUL(0.2f, lg);
                float v  = (mb & (1u << t)) ? lr : FADD(lr, MASKC);
                ev[kb][t] = v;
                Mloc = fmaxf(Mloc, v);
            }
        }
        // ---- M: order-free cross-lane max over the row's 4 lanes
        Mloc = fmaxf(Mloc, __shfl_xor(Mloc, 16, 64));
        Mloc = fmaxf(Mloc, __shfl_xor(Mloc, 32, 64));
        const float Mi = Mloc;

        // ---- exp ONCE
#pragma unroll
        for (int kb = 0; kb < 8; ++kb)
#pragma unroll
            for (int t = 0; t < 8; ++t)
                ev[kb][t] = expf_cr(FSUB(ev[kb][t], Mi));

        // ---- S: numpy pairwise tree via shuffles (exact; FADD commutative)
        float blkS[2];
#pragma unroll
        for (int blk = 0; blk < 2; ++blk) {
            float d[8];
#pragma unroll
            for (int t = 0; t < 8; ++t) {
                float s0 = FADD(ev[blk * 4 + 0][t], __shfl_xor(ev[blk * 4 + 0][t], 32, 64));
                float s1 = FADD(ev[blk * 4 + 1][t], __shfl_xor(ev[blk * 4 + 1][t], 32, 64));
                float s2 = FADD(ev[blk * 4 + 2][t], __shfl_xor(ev[blk * 4 + 2][t], 32, 64));
                float s3 = FADD(ev[blk * 4 + 3][t], __shfl_xor(ev[blk * 4 + 3][t], 32, 64));
                float cc = FADD(FADD(s0, s1), FADD(s2, s3));   // c[l]
                d[t] = FADD(cc, __shfl_xor(cc, 16, 64));       // d[l] = c[l]+c[l+8]
            }
            float e4[4], f2[2];
#pragma unroll
            for (int t = 0; t < 4; ++t) e4[t] = FADD(d[t], d[t + 4]);
            f2[0] = FADD(e4[0], e4[2]);
            f2[1] = FADD(e4[1], e4[3]);
            blkS[blk] = FADD(f2[0], f2[1]);
        }
        const float Si = FADD(blkS[0], blkS[1]);

        // ---- p, view accumulate, PV MFMA
        s16x8 pfrag[8];
#pragma unroll
        for (int kb = 0; kb < 8; ++kb) {
            s16x8 pf;
#pragma unroll
            for (int t = 0; t < 8; ++t) {
                float p = FDIV(ev[kb][t], Si);
                view_acc[kb][t] = FADD(view_acc[kb][t], FMUL(p, 0.125f));
                pf[t] = (short)f2bf(p);
            }
            pfrag[kb] = pf;
        }

        fx4 acc[4] = {};
#pragma unroll
        for (int kb = 0; kb < 8; ++kb) {
            int jo = kb * 32 + jq * 8;
#pragma unroll
            for (int nf = 0; nf < 4; ++nf) {
                s16x8 vf = *(const s16x8*)&Vt[(nf * 16 + m) * VT_STRIDE + jo];
                acc[nf] = mfma_bf16_16x16x32(pfrag[kb], vf, acc[nf]);
            }
        }
#pragma unroll
        for (int nf = 0; nf < 4; ++nf) {
            float bias = biases[h * 64 + nf * 16 + m];
#pragma unroll
            for (int r = 0; r < 4; ++r) {
                float val = acc[nf][r] + bias;
                val = val > 0.f ? val : 0.f;
                int gi = (b << 8) + row0 + w * 16 + jq * 4 + r;
                out0[gi * 512 + h * 64 + nf * 16 + m] = val;
            }
        }
    }

#pragma unroll
    for (int kb = 0; kb < 8; ++kb) {
        int base = (((b << 8) + myrow) << 8) + kb * 32 + jq * 8;
        float4 v0, v1;
        v0.x = view_acc[kb][0]; v0.y = view_acc[kb][1]; v0.z = view_acc[kb][2]; v0.w = view_acc[kb][3];
        v1.x = view_acc[kb][4]; v1.y = view_acc[kb][5]; v1.z = view_acc[kb][6]; v1.w = view_acc[kb][7];
        *(float4*)&view32[base]     = v0;
        *(float4*)&view32[base + 4] = v1;
    }
}

// ---------------------------------------------------------------- pool / temp / thresh
__global__ __launch_bounds__(256) void pool_emu(const float* __restrict__ view32,
                                                float* __restrict__ pooled) {
    int t = blockIdx.x * 256 + threadIdx.x;      // 2,097,152
    int j = t & 127, i = (t >> 7) & 127, b = t >> 14;
    const float* p = &view32[(b << 16) + (2 * i) * 256 + 2 * j];
    pooled[t] = fmaxf(fmaxf(p[0], p[1]), fmaxf(p[256], p[257]));
}

// temp[b,i,k] = SSE dot over j=0..127: pooled row (contig) x alpha[:,k] (stride 128)
__global__ __launch_bounds__(256) void temp_emu(const float* __restrict__ pooled,
                                                const float* __restrict__ alpha,
                                                float* __restrict__ temp) {
    int t = blockIdx.x * 256 + threadIdx.x;      // 2,097,152
    int k = t & 127, i = (t >> 7) & 127, b = t >> 14;
    const float* pr = &pooled[(b << 14) + i * 128];
    const float* ap = &alpha[k];                  // stride 128 over j
    float a0 = 0.f, a1 = 0.f, a2 = 0.f, a3 = 0.f;
    for (int j = 0; j < 128; j += 8) {
        a0 = FADD(a0, FMUL(pr[j + 0], ap[(j + 0) * 128]));
        a1 = FADD(a1, FMUL(pr[j + 1], ap[(j + 1) * 128]));
        a2 = FADD(a2, FMUL(pr[j + 2], ap[(j + 2) * 128]));
        a3 = FADD(a3, FMUL(pr[j + 3], ap[(j + 3) * 128]));
        a0 = FADD(a0, FMUL(pr[j + 4], ap[(j + 4) * 128]));
        a1 = FADD(a1, FMUL(pr[j + 5], ap[(j + 5) * 128]));
        a2 = FADD(a2, FMUL(pr[j + 6], ap[(j + 6) * 128]));
        a3 = FADD(a3, FMUL(pr[j + 7], ap[(j + 7) * 128]));
    }
    temp[t] = FADD(FADD(a0, a1), FADD(a2, a3));
}

// s[b] = numpy pairwise over 16384 (128 leaves of pw128, balanced binary tree)
__global__ __launch_bounds__(128) void thresh_emu(const float* __restrict__ temp,
                                                  float* __restrict__ thresh32) {
    __shared__ float red[128];
    int l = threadIdx.x, b = blockIdx.x;
    red[l] = pw128(&temp[(b << 14) + l * 128]);
    __syncthreads();
    for (int s = 64; s >= 1; s >>= 1) {
        float v = 0.f;
        if (l < s) v = FADD(red[2 * l], red[2 * l + 1]);
        __syncthreads();
        if (l < s) red[l] = v;
        __syncthreads();
    }
    if (l == 0) {
        float sfin = red[0];
        float e = expf_cr(-sfin);                 // np.exp(-s) fp32 (correctly rounded)
        thresh32[b] = FDIV(1.0f, FADD(1.0f, e)); // 1/(1+e)
    }
}

// ---------------------------------------------------------------- binarize (fp32)
__global__ __launch_bounds__(256) void binarize_emu(const float* __restrict__ view32,
                                                    const float* __restrict__ thresh32,
                                                    float* __restrict__ out1) {
    int g = blockIdx.x * 256 + threadIdx.x;
    int e = g * 4;
    int b = e >> 16, i = (e >> 8) & 255, j = e & 255;
    float th = thresh32[b];
    float4 v = *(const float4*)&view32[e];
    float4 o;
    o.x = (FADD(v.x, (i == j + 0) ? 1.f : 0.f) < th) ? 1.f : 0.f;
    o.y = (FADD(v.y, (i == j + 1) ? 1.f : 0.f) < th) ? 1.f : 0.f;
    o.z = (FADD(v.z, (i == j + 2) ? 1.f : 0.f) < th) ? 1.f : 0.f;
    o.w = (FADD(v.w, (i == j + 3) ? 1.f : 0.f) < th) ? 1.f : 0.f;
    *(float4*)&out1[e] = o;
}

// ---------------------------------------------------------------- launch
static inline void ck_launch(const char* name) {
    hipError_t e = hipGetLastError();
    if (e != hipSuccess)
        fprintf(stderr, "[gat] %s launch error %d: %s\n", name, (int)e, hipGetErrorString(e));
}

extern "C" void kernel_launch(void* const* d_in, const int* in_sizes, int n_in,
                              void* d_out, int out_size, void* d_ws, size_t ws_size,
                              hipStream_t stream) {
    const float* X      = (const float*)d_in[0];
    const float* A      = (const float*)d_in[1];
    const float* kern   = (const float*)d_in[2];
    const float* biases = (const float*)d_in[3];
    const float* attn_s = (const float*)d_in[4];
    const float* attn_n = (const float*)d_in[5];
    const float* alpha  = (const float*)d_in[6];

    char* ws = (char*)d_ws;
    unsigned short* feats_bf = (unsigned short*)(ws);             //  33,554,432 B
    float*          feats32  = (float*)(ws + 33554432);           //  67,108,864 B
    float*          view32   = (float*)(ws + 100663296);          //  33,554,432 B
    float*          a_s32    = (float*)(ws + 134217728);          //   1,048,576 B
    float*          a_n32    = (float*)(ws + 135266304);          //   1,048,576 B
    float*          pooled   = (float*)(ws + 136314880);          //   8,388,608 B
    float*          temp     = (float*)(ws + 144703488);          //   8,388,608 B
    float*          thresh32 = (float*)(ws + 153092096);          //         512 B
    unsigned short* wkt      = (unsigned short*)(ws + 153092608); //     524,288 B

    // kern_r (8 MB) aliased onto view32's region: dead until attn_emu writes
    // view32, and feats32_emu4 (the only reader) runs strictly before that.
    float*          kern_r   = (float*)(ws + 100663296);

    float* out0 = (float*)d_out;
    float* out1 = out0 + 16777216;

    repack_w    <<<1024, 256, 0, stream>>>(kern, wkt);              ck_launch("repack_w");
    repack_k32  <<<1024, 256, 0, stream>>>(kern, kern_r);           ck_launch("repack_k32");
    gemm_feats  <<<1024, 256, 0, stream>>>(X, wkt, feats_bf);       ck_launch("gemm_feats");
    feats32_emu4<<<2048, 512, 0, stream>>>(X, kern_r, feats32);     ck_launch("feats32_emu4");
    logits_emu  <<<1024, 256, 0, stream>>>(feats32, attn_s, attn_n, a_s32, a_n32);
                                                                    ck_launch("logits_emu");
    attn_emu    <<<512, 256, 0, stream>>>(A, feats_bf, a_s32, a_n32, biases, out0, view32);
                                                                    ck_launch("attn_emu");
    pool_emu    <<<8192, 256, 0, stream>>>(view32, pooled);         ck_launch("pool_emu");
    temp_emu    <<<8192, 256, 0, stream>>>(pooled, alpha, temp);    ck_launch("temp_emu");
    thresh_emu  <<<128, 128, 0, stream>>>(temp, thresh32);          ck_launch("thresh_emu");
    binarize_emu<<<8192, 256, 0, stream>>>(view32, thresh32, out1); ck_launch("binarize_emu");
}